// Round 1
// baseline (1081.670 us; speedup 1.0000x reference)
//
#include <hip/hip_runtime.h>
#include <hip/hip_bf16.h>
#include <math.h>

#define T_ 2048
#define H_ 16
#define KH_ 2
#define G_ 8
#define D_ 128
#define NCMP 127
#define NBLK 32
#define TOPN 16
#define WIN_ 512
#define KPAD 132
#define SCALE 0.08838834764831845f

// ---------------- kernel 1: build compressed (mean-pooled) K/V ----------------
// grid: KH*NCMP blocks, 128 threads. cmp layout: [kh][j][d]
__global__ void build_cmp(const float* __restrict__ k, const float* __restrict__ v,
                          float* __restrict__ cmpk, float* __restrict__ cmpv) {
    int j  = blockIdx.x % NCMP;
    int kh = blockIdx.x / NCMP;
    int d  = threadIdx.x;
    int s0 = j * 16;
    float sk = 0.f, sv = 0.f;
    for (int i = 0; i < 32; ++i) {
        sk += k[(size_t)(s0 + i) * KH_ * D_ + kh * D_ + d];
        sv += v[(size_t)(s0 + i) * KH_ * D_ + kh * D_ + d];
    }
    cmpk[(kh * NCMP + j) * D_ + d] = sk * (1.f / 32.f);
    cmpv[(kh * NCMP + j) * D_ + d] = sv * (1.f / 32.f);
}

// ---------------- kernel 2: compressed attention + top-16 block selection ----
// grid: T*KH blocks (bid = t*KH + kh), 256 threads.
// Writes w0*o_cmp into out, and the selected-block bitmask into sel[kh][t].
__global__ __launch_bounds__(256) void cmp_attn_select(
        const float* __restrict__ q, const float* __restrict__ w,
        const float* __restrict__ cmpk, const float* __restrict__ cmpv,
        float* __restrict__ out, unsigned int* __restrict__ sel) {
    int bid = blockIdx.x;
    int kh  = bid & 1;
    int t   = bid >> 1;
    int tid = threadIdx.x;

    __shared__ float qs[G_ * D_];     // 8 q rows
    __shared__ float ls[G_ * NCMP];   // logits -> p
    __shared__ float wsc[NCMP];       // per-window score (summed over g)
    __shared__ float bsc[NBLK];       // per-block score

    for (int i = tid; i < G_ * D_; i += 256) {
        int g = i >> 7, d = i & 127;
        qs[i] = q[(size_t)t * H_ * D_ + (kh * G_ + g) * D_ + d];
    }
    __syncthreads();

    int nv = (t >= 31) ? (((t - 31) >> 4) + 1) : 0;   // valid window prefix
    if (nv > NCMP) nv = NCMP;

    // logits (fp32, float4 vectorized)
    for (int idx = tid; idx < G_ * NCMP; idx += 256) {
        int g = idx / NCMP, j = idx % NCMP;
        float acc = 0.f;
        if (j < nv) {
            const float4* kr4 = reinterpret_cast<const float4*>(cmpk + (kh * NCMP + j) * D_);
            const float4* qr4 = reinterpret_cast<const float4*>(&qs[g * D_]);
#pragma unroll
            for (int d4 = 0; d4 < D_ / 4; ++d4) {
                float4 a = qr4[d4], b = kr4[d4];
                acc += a.x * b.x + a.y * b.y + a.z * b.z + a.w * b.w;
            }
            acc *= SCALE;
        }
        ls[g * NCMP + j] = acc;
    }
    __syncthreads();

    // softmax per head: 32-lane subgroup per head g = tid>>5
    {
        int g = tid >> 5, l = tid & 31;
        if (nv > 0) {
            float m = -INFINITY;
            for (int j = l; j < nv; j += 32) m = fmaxf(m, ls[g * NCMP + j]);
            for (int o = 16; o; o >>= 1) m = fmaxf(m, __shfl_xor(m, o, 32));
            float ssum = 0.f;
            for (int j = l; j < nv; j += 32) {
                float e = expf(ls[g * NCMP + j] - m);
                ls[g * NCMP + j] = e;
                ssum += e;
            }
            for (int o = 16; o; o >>= 1) ssum += __shfl_xor(ssum, o, 32);
            float inv = 1.f / ssum;
            for (int j = l; j < NCMP; j += 32)
                ls[g * NCMP + j] = (j < nv) ? ls[g * NCMP + j] * inv : 0.f;
        } else {
            for (int j = l; j < NCMP; j += 32) ls[g * NCMP + j] = 0.f;
        }
    }
    __syncthreads();

    // o_cmp = p @ cmp_v, scaled by w0, written to out
    for (int idx = tid; idx < G_ * D_; idx += 256) {
        int g = idx >> 7, d = idx & 127;
        float acc = 0.f;
        for (int j = 0; j < nv; ++j)
            acc += ls[g * NCMP + j] * cmpv[(kh * NCMP + j) * D_ + d];
        int h = kh * G_ + g;
        out[(size_t)t * H_ * D_ + h * D_ + d] = w[(size_t)t * H_ * 3 + h * 3 + 0] * acc;
    }

    // window scores summed over group heads
    if (tid < NCMP) {
        float s = 0.f;
        for (int g = 0; g < G_; ++g) s += ls[g * NCMP + tid];
        wsc[tid] = s;
    }
    __syncthreads();

    // block scores: window j overlaps block b iff 4b-1 <= j <= 4b+3
    if (tid < NBLK) {
        int b = tid;
        float sc = 0.f;
        int j0 = 4 * b - 1; if (j0 < 0) j0 = 0;
        int j1 = 4 * b + 3; if (j1 > NCMP - 1) j1 = NCMP - 1;
        for (int j = j0; j <= j1; ++j) sc += wsc[j];
        int tb = t >> 6;
        bool forced = (b == 0) || (b <= tb && b >= tb - 1);
        if (forced) sc = 1e30f;
        if (b * 64 > t) sc = -1e30f;   // invalid
        bsc[b] = sc;
    }
    __syncthreads();

    // stable top-16 via rank count (matches jax.lax.top_k tie-breaking)
    if (tid < 64) {
        bool selbit = false;
        if (tid < NBLK) {
            float sb = bsc[tid];
            int cnt = 0;
            for (int b2 = 0; b2 < NBLK; ++b2) {
                float s2 = bsc[b2];
                cnt += (s2 > sb) || (s2 == sb && b2 < tid);
            }
            selbit = (cnt < TOPN);
        }
        unsigned long long bal = __ballot(selbit);
        if (tid == 0) sel[kh * T_ + t] = (unsigned int)bal;
    }
}

// ---------------- kernel 3: fused window + selected attention ----------------
// grid: T*KH blocks (bid = t*KH + kh), 256 threads; 8 group heads per block.
// mode 0 = sliding window (weight w2), mode 1 = selected blocks (weight w1).
// Accumulates into out (which already holds w0*o_cmp).
__global__ __launch_bounds__(256) void slc_win_attn(
        const float* __restrict__ q, const float* __restrict__ k,
        const float* __restrict__ v, const float* __restrict__ w,
        const unsigned int* __restrict__ sel, float* __restrict__ out) {
    int bid = blockIdx.x;
    int kh  = bid & 1;
    int t   = bid >> 1;
    int tid = threadIdx.x;
    int g   = tid >> 5;   // head within group
    int l   = tid & 31;   // lane within subgroup

    __shared__ float qs[G_][D_];
    __shared__ float kbuf[64][KPAD];
    __shared__ float vbuf[64][KPAD];
    __shared__ float ps[G_][64];

    for (int i = tid; i < G_ * D_; i += 256)
        qs[i >> 7][i & 127] = q[(size_t)t * H_ * D_ + (kh * G_ + (i >> 7)) * D_ + (i & 127)];

    int tb  = t >> 6;
    int wlo = t - WIN_ + 1; if (wlo < 0) wlo = 0;

    float ow0 = 0.f, ow1 = 0.f, ow2 = 0.f, ow3 = 0.f;

    for (int mode = 0; mode < 2; ++mode) {
        float m_run = -INFINITY, l_run = 0.f;
        float o0 = 0.f, o1 = 0.f, o2 = 0.f, o3 = 0.f;

        unsigned int mask = 0;
        int b = 0;
        if (mode == 0) {
            b = wlo >> 6;
        } else {
            mask = sel[kh * T_ + t];
            unsigned int vm = (tb >= 31) ? 0xFFFFFFFFu : ((2u << tb) - 1u);
            mask &= vm;   // keep only blocks with tokens <= t
        }

        while (true) {
            if (mode == 0) {
                if (b > tb) break;
            } else {
                if (!mask) break;
                b = __ffs(mask) - 1;
                mask &= mask - 1;
            }
            int s0 = b << 6;

            __syncthreads();   // previous chunk fully consumed
            // stage K,V chunk: 2048 float4 loads, coalesced (2 rows/instr)
            for (int i = tid; i < 64 * 32; i += 256) {
                int r = i >> 5, d4 = i & 31;
                const float4* srck = reinterpret_cast<const float4*>(
                    k + (size_t)(s0 + r) * KH_ * D_ + kh * D_) + d4;
                const float4* srcv = reinterpret_cast<const float4*>(
                    v + (size_t)(s0 + r) * KH_ * D_ + kh * D_) + d4;
                *reinterpret_cast<float4*>(&kbuf[r][d4 * 4]) = *srck;
                *reinterpret_cast<float4*>(&vbuf[r][d4 * 4]) = *srcv;
            }
            __syncthreads();

            // logits: thread (g, l) does keys l and l+32
            float lg0, lg1;
#pragma unroll
            for (int hh = 0; hh < 2; ++hh) {
                int kk = l + 32 * hh;
                int s  = s0 + kk;
                bool ok = (s <= t) && (mode == 1 || s >= wlo);
                float acc = 0.f;
                const float4* kr4 = reinterpret_cast<const float4*>(&kbuf[kk][0]);
                const float4* qr4 = reinterpret_cast<const float4*>(&qs[g][0]);
#pragma unroll
                for (int d4 = 0; d4 < D_ / 4; ++d4) {
                    float4 a = qr4[d4], bb = kr4[d4];
                    acc += a.x * bb.x + a.y * bb.y + a.z * bb.z + a.w * bb.w;
                }
                float lg = ok ? acc * SCALE : -INFINITY;
                if (hh == 0) lg0 = lg; else lg1 = lg;
            }

            // online softmax (per 32-lane subgroup = per head)
            float mc = fmaxf(lg0, lg1);
            for (int o = 16; o; o >>= 1) mc = fmaxf(mc, __shfl_xor(mc, o, 32));
            float mnew = fmaxf(m_run, mc);
            float f  = __expf(m_run - mnew);   // first chunk: exp(-inf)=0
            float p0 = __expf(lg0 - mnew);
            float p1 = __expf(lg1 - mnew);
            ps[g][l]      = p0;
            ps[g][l + 32] = p1;
            float lsum = p0 + p1;
            for (int o = 16; o; o >>= 1) lsum += __shfl_xor(lsum, o, 32);
            l_run = l_run * f + lsum;
            m_run = mnew;
            o0 *= f; o1 *= f; o2 *= f; o3 *= f;

            // PV: thread (g, l) owns dims 4l..4l+3  (ps written by same wave)
            const float* vb;
#pragma unroll 8
            for (int kk = 0; kk < 64; ++kk) {
                float p = ps[g][kk];
                vb = &vbuf[kk][4 * l];
                o0 += p * vb[0]; o1 += p * vb[1]; o2 += p * vb[2]; o3 += p * vb[3];
            }

            if (mode == 0) ++b;
        }

        float inv = 1.f / l_run;
        float wgt = w[(size_t)t * H_ * 3 + (kh * G_ + g) * 3 + (mode == 0 ? 2 : 1)];
        ow0 += wgt * o0 * inv;
        ow1 += wgt * o1 * inv;
        ow2 += wgt * o2 * inv;
        ow3 += wgt * o3 * inv;
    }

    // accumulate into out (already holds w0*o_cmp)
    float* op = out + (size_t)t * H_ * D_ + (kh * G_ + g) * D_ + 4 * l;
    op[0] += ow0; op[1] += ow1; op[2] += ow2; op[3] += ow3;
}

// ---------------- launch ----------------
extern "C" void kernel_launch(void* const* d_in, const int* in_sizes, int n_in,
                              void* d_out, int out_size, void* d_ws, size_t ws_size,
                              hipStream_t stream) {
    const float* q = (const float*)d_in[0];
    const float* k = (const float*)d_in[1];
    const float* v = (const float*)d_in[2];
    const float* w = (const float*)d_in[3];
    float* out = (float*)d_out;

    float* cmpk = (float*)d_ws;
    float* cmpv = cmpk + KH_ * NCMP * D_;
    unsigned int* sel = (unsigned int*)(cmpv + KH_ * NCMP * D_);

    hipLaunchKernelGGL(build_cmp, dim3(KH_ * NCMP), dim3(128), 0, stream, k, v, cmpk, cmpv);
    hipLaunchKernelGGL(cmp_attn_select, dim3(T_ * KH_), dim3(256), 0, stream,
                       q, w, cmpk, cmpv, out, sel);
    hipLaunchKernelGGL(slc_win_attn, dim3(T_ * KH_), dim3(256), 0, stream,
                       q, k, v, w, sel, out);
}

// Round 3
// 461.635 us; speedup vs baseline: 2.3431x; 2.3431x over previous
//
#include <hip/hip_runtime.h>
#include <hip/hip_bf16.h>
#include <math.h>

#define T_ 2048
#define H_ 16
#define KH_ 2
#define G_ 8
#define D_ 128
#define NCMP 127
#define NBLK 32
#define TOPN 16
#define WIN_ 512
#define SCALE 0.08838834764831845f

typedef __attribute__((ext_vector_type(8))) short short8;
typedef __attribute__((ext_vector_type(16))) float f32x16;

__device__ __forceinline__ unsigned short f2bf(float x) {
    union { float f; unsigned u; } c; c.f = x;
    unsigned u = c.u + 0x7fffu + ((c.u >> 16) & 1u);
    return (unsigned short)(u >> 16);
}

// ---------------- kernel 1: build compressed (mean-pooled) K/V ----------------
__global__ void build_cmp(const float* __restrict__ k, const float* __restrict__ v,
                          float* __restrict__ cmpk, float* __restrict__ cmpv) {
    int j  = blockIdx.x % NCMP;
    int kh = blockIdx.x / NCMP;
    int d  = threadIdx.x;
    int s0 = j * 16;
    float sk = 0.f, sv = 0.f;
    for (int i = 0; i < 32; ++i) {
        sk += k[(size_t)(s0 + i) * KH_ * D_ + kh * D_ + d];
        sv += v[(size_t)(s0 + i) * KH_ * D_ + kh * D_ + d];
    }
    cmpk[(kh * NCMP + j) * D_ + d] = sk * (1.f / 32.f);
    cmpv[(kh * NCMP + j) * D_ + d] = sv * (1.f / 32.f);
}

// ---------------- kernel 2: compressed attention + top-16 block selection ----
// fp32 on purpose: block selection is discrete; must match numpy top_k closely.
__global__ __launch_bounds__(256) void cmp_attn_select(
        const float* __restrict__ q, const float* __restrict__ w,
        const float* __restrict__ cmpk, const float* __restrict__ cmpv,
        float* __restrict__ out, unsigned int* __restrict__ sel) {
    int bid = blockIdx.x;
    int kh  = bid & 1;
    int t   = bid >> 1;
    int tid = threadIdx.x;

    __shared__ float qs[G_ * D_];
    __shared__ float ls[G_ * NCMP];
    __shared__ float wsc[NCMP];
    __shared__ float bsc[NBLK];

    for (int i = tid; i < G_ * D_; i += 256) {
        int g = i >> 7, d = i & 127;
        qs[i] = q[(size_t)t * H_ * D_ + (kh * G_ + g) * D_ + d];
    }
    __syncthreads();

    int nv = (t >= 31) ? (((t - 31) >> 4) + 1) : 0;
    if (nv > NCMP) nv = NCMP;

    for (int idx = tid; idx < G_ * NCMP; idx += 256) {
        int g = idx / NCMP, j = idx % NCMP;
        float acc = 0.f;
        if (j < nv) {
            const float4* kr4 = reinterpret_cast<const float4*>(cmpk + (kh * NCMP + j) * D_);
            const float4* qr4 = reinterpret_cast<const float4*>(&qs[g * D_]);
#pragma unroll
            for (int d4 = 0; d4 < D_ / 4; ++d4) {
                float4 a = qr4[d4], b = kr4[d4];
                acc += a.x * b.x + a.y * b.y + a.z * b.z + a.w * b.w;
            }
            acc *= SCALE;
        }
        ls[g * NCMP + j] = acc;
    }
    __syncthreads();

    {
        int g = tid >> 5, l = tid & 31;
        if (nv > 0) {
            float m = -INFINITY;
            for (int j = l; j < nv; j += 32) m = fmaxf(m, ls[g * NCMP + j]);
            for (int o = 16; o; o >>= 1) m = fmaxf(m, __shfl_xor(m, o, 32));
            float ssum = 0.f;
            for (int j = l; j < nv; j += 32) {
                float e = expf(ls[g * NCMP + j] - m);
                ls[g * NCMP + j] = e;
                ssum += e;
            }
            for (int o = 16; o; o >>= 1) ssum += __shfl_xor(ssum, o, 32);
            float inv = 1.f / ssum;
            for (int j = l; j < NCMP; j += 32)
                ls[g * NCMP + j] = (j < nv) ? ls[g * NCMP + j] * inv : 0.f;
        } else {
            for (int j = l; j < NCMP; j += 32) ls[g * NCMP + j] = 0.f;
        }
    }
    __syncthreads();

    for (int idx = tid; idx < G_ * D_; idx += 256) {
        int g = idx >> 7, d = idx & 127;
        float acc = 0.f;
        for (int j = 0; j < nv; ++j)
            acc += ls[g * NCMP + j] * cmpv[(kh * NCMP + j) * D_ + d];
        int h = kh * G_ + g;
        out[(size_t)t * H_ * D_ + h * D_ + d] = w[(size_t)t * H_ * 3 + h * 3 + 0] * acc;
    }

    if (tid < NCMP) {
        float s = 0.f;
        for (int g = 0; g < G_; ++g) s += ls[g * NCMP + tid];
        wsc[tid] = s;
    }
    __syncthreads();

    if (tid < NBLK) {
        int b = tid;
        float sc = 0.f;
        int j0 = 4 * b - 1; if (j0 < 0) j0 = 0;
        int j1 = 4 * b + 3; if (j1 > NCMP - 1) j1 = NCMP - 1;
        for (int j = j0; j <= j1; ++j) sc += wsc[j];
        int tb = t >> 6;
        bool forced = (b == 0) || (b <= tb && b >= tb - 1);
        if (forced) sc = 1e30f;
        if (b * 64 > t) sc = -1e30f;
        bsc[b] = sc;
    }
    __syncthreads();

    if (tid < 64) {
        bool selbit = false;
        if (tid < NBLK) {
            float sb = bsc[tid];
            int cnt = 0;
            for (int b2 = 0; b2 < NBLK; ++b2) {
                float s2 = bsc[b2];
                cnt += (s2 > sb) || (s2 == sb && b2 < tid);
            }
            selbit = (cnt < TOPN);
        }
        unsigned long long bal = __ballot(selbit);
        if (tid == 0) sel[kh * T_ + t] = (unsigned int)bal;
    }
}

// ---------------- kernel 3: MFMA flash window+selected attention -------------
// grid (T/16, KH, phase): phase 0 = window (w2), 1 = selected (w1).
// Block: 256 thr = 4 waves; wave wv handles 32 rows = 16 queries x heads {2wv, 2wv+1}.
// Swapped QK: S^T = mfma(A=K_tile, B=Q^T) so lane owns a full P column (its combo).
// NOTE: the softmax running max m_run is WAVE-UNIFORM (full 64-lane max), so the
// rescale factor f is identical for every accumulator row. This is required:
// acc[dt][r] holds output row crow(r,hi) != the lane's own combo l31, so any
// per-combo f would be applied to the wrong rows (round-2 bug, absmax 2.5).
// Online softmax stays exact with a reference >= per-row max; per-combo l_run
// still normalizes each row exactly (routed through wfac[crow] in the epilogue).
__global__ __launch_bounds__(256, 2) void slc_win_mfma(
        const float* __restrict__ q, const float* __restrict__ k,
        const float* __restrict__ v, const float* __restrict__ w,
        const unsigned int* __restrict__ sel, float* __restrict__ out) {
    const int qt    = blockIdx.x;
    const int kh    = blockIdx.y;
    const int phase = blockIdx.z;
    const int t0    = qt * 16;
    const int tid   = threadIdx.x;
    const int wv    = tid >> 6;
    const int lane  = tid & 63;
    const int l31   = lane & 31;
    const int hi    = lane >> 5;
    const int hi4   = hi * 4;

    __shared__ unsigned short Kl[64 * 128];   // bf16, XOR-swizzled [key][d]
    __shared__ unsigned short VT[128 * 64];   // bf16, XOR-swizzled V^T [d][key]
    __shared__ float wfac[4][32];

    const int qloc = l31 & 15;
    const int t    = t0 + qloc;
    const int hloc = 2 * wv + (l31 >> 4);
    const int h    = kh * G_ + hloc;

    // Q fragments (B-operand): lane holds Q[row=l31][d = dc*16 + hi*8 + j]
    short8 qf[8];
    {
        const float* qrow = q + (size_t)t * (H_ * D_) + h * D_;
#pragma unroll
        for (int dc = 0; dc < 8; ++dc) {
            int d0 = dc * 16 + hi * 8;
            float4 x = *reinterpret_cast<const float4*>(qrow + d0);
            float4 y = *reinterpret_cast<const float4*>(qrow + d0 + 4);
            short8 f;
            f[0] = (short)f2bf(x.x); f[1] = (short)f2bf(x.y);
            f[2] = (short)f2bf(x.z); f[3] = (short)f2bf(x.w);
            f[4] = (short)f2bf(y.x); f[5] = (short)f2bf(y.y);
            f[6] = (short)f2bf(y.z); f[7] = (short)f2bf(y.w);
            qf[dc] = f;
        }
    }

    const unsigned int smask = sel[kh * T_ + t];
    const int tbmax = t0 >> 6;
    unsigned int um = 0;
    int b0 = 0;
    if (phase == 0) {
        int lo = t0 - (WIN_ - 1); if (lo < 0) lo = 0;
        b0 = lo >> 6;
    } else {
        unsigned int vm = (tbmax >= 31) ? 0xffffffffu : ((2u << tbmax) - 1u);
        um = smask;
        um |= __shfl_xor(um, 1); um |= __shfl_xor(um, 2);
        um |= __shfl_xor(um, 4); um |= __shfl_xor(um, 8);
        um &= vm;
    }

    f32x16 acc[4];
#pragma unroll
    for (int dt = 0; dt < 4; ++dt)
#pragma unroll
        for (int r = 0; r < 16; ++r) acc[dt][r] = 0.f;
    float m_run = -1e30f, l_run = 0.f;

    int bidx = b0;
    unsigned int rem = um;
    while (true) {
        int b;
        if (phase == 0) { if (bidx > tbmax) break; b = bidx++; }
        else            { if (!rem) break; b = __ffs(rem) - 1; rem &= rem - 1; }
        const int s0 = b << 6;

        __syncthreads();
        // ---- stage K and V^T (fp32 -> bf16, swizzled) ----
#pragma unroll
        for (int it = 0; it < 8; ++it) {
            int i = tid + it * 256;
            int r = i >> 5, c4 = i & 31;
            const float* kp = k + (size_t)(s0 + r) * (KH_ * D_) + kh * D_ + c4 * 4;
            float4 kx = *reinterpret_cast<const float4*>(kp);
            ushort4 kb;
            kb.x = f2bf(kx.x); kb.y = f2bf(kx.y); kb.z = f2bf(kx.z); kb.w = f2bf(kx.w);
            *reinterpret_cast<ushort4*>(
                &Kl[r * 128 + (((c4 >> 1) ^ (r & 7)) << 3) + (c4 & 1) * 4]) = kb;
            const float* vp = v + (size_t)(s0 + r) * (KH_ * D_) + kh * D_ + c4 * 4;
            float4 vx = *reinterpret_cast<const float4*>(vp);
            int d0 = c4 * 4;
            VT[(d0+0) * 64 + ((((r >> 3)) ^ ((d0+0) & 7)) << 3) + (r & 7)] = f2bf(vx.x);
            VT[(d0+1) * 64 + ((((r >> 3)) ^ ((d0+1) & 7)) << 3) + (r & 7)] = f2bf(vx.y);
            VT[(d0+2) * 64 + ((((r >> 3)) ^ ((d0+2) & 7)) << 3) + (r & 7)] = f2bf(vx.z);
            VT[(d0+3) * 64 + ((((r >> 3)) ^ ((d0+3) & 7)) << 3) + (r & 7)] = f2bf(vx.w);
        }
        __syncthreads();

        // ---- QK^T (swapped): S^T[key][combo] ----
        f32x16 s_[2];
#pragma unroll
        for (int r = 0; r < 16; ++r) { s_[0][r] = 0.f; s_[1][r] = 0.f; }
#pragma unroll
        for (int dc = 0; dc < 8; ++dc) {
            int c8 = dc * 2 + hi;
            short8 a0 = *reinterpret_cast<const short8*>(
                &Kl[l31 * 128 + ((c8 ^ (l31 & 7)) << 3)]);
            short8 a1 = *reinterpret_cast<const short8*>(
                &Kl[(32 + l31) * 128 + ((c8 ^ (l31 & 7)) << 3)]);
            s_[0] = __builtin_amdgcn_mfma_f32_32x32x16_bf16(a0, qf[dc], s_[0], 0, 0, 0);
            s_[1] = __builtin_amdgcn_mfma_f32_32x32x16_bf16(a1, qf[dc], s_[1], 0, 0, 0);
        }

        // ---- mask + online softmax (lane's values = column for combo l31) ----
        const int sb = (smask >> b) & 1;
        float p_[2][16];
        float mc = -INFINITY;
#pragma unroll
        for (int sub = 0; sub < 2; ++sub)
#pragma unroll
            for (int r = 0; r < 16; ++r) {
                int crow = (r & 3) + 8 * (r >> 2) + hi4;
                int s = s0 + sub * 32 + crow;
                bool ok = (s <= t) && (phase ? (sb != 0) : (s + WIN_ > t));
                float lg = ok ? s_[sub][r] * SCALE : -INFINITY;
                p_[sub][r] = lg;
                mc = fmaxf(mc, lg);
            }
        // WAVE-UNIFORM max (all 64 lanes agree) -> f valid for all acc rows
        mc = fmaxf(mc, __shfl_xor(mc, 1));
        mc = fmaxf(mc, __shfl_xor(mc, 2));
        mc = fmaxf(mc, __shfl_xor(mc, 4));
        mc = fmaxf(mc, __shfl_xor(mc, 8));
        mc = fmaxf(mc, __shfl_xor(mc, 16));
        mc = fmaxf(mc, __shfl_xor(mc, 32));
        float mnew = fmaxf(m_run, mc);
        float f = __expf(m_run - mnew);
        float lsum = 0.f;
#pragma unroll
        for (int sub = 0; sub < 2; ++sub)
#pragma unroll
            for (int r = 0; r < 16; ++r) {
                float e = __expf(p_[sub][r] - mnew);
                p_[sub][r] = e;
                lsum += e;
            }
        lsum += __shfl_xor(lsum, 32);   // per-combo row sum (partner holds other 32 keys)
        l_run = l_run * f + lsum;
        m_run = mnew;
#pragma unroll
        for (int dt = 0; dt < 4; ++dt)
#pragma unroll
            for (int r = 0; r < 16; ++r) acc[dt][r] *= f;

        // ---- P -> bf16 A-fragments, PV ----
#pragma unroll
        for (int kc = 0; kc < 4; ++kc) {
            const int su = kc >> 1, rb = (kc & 1) * 8;
            unsigned pa0, pb0, pa1, pb1;
            asm("v_cvt_pk_bf16_f32 %0, %1, %2" : "=v"(pa0) : "v"(p_[su][rb+0]), "v"(p_[su][rb+1]));
            asm("v_cvt_pk_bf16_f32 %0, %1, %2" : "=v"(pa1) : "v"(p_[su][rb+2]), "v"(p_[su][rb+3]));
            asm("v_cvt_pk_bf16_f32 %0, %1, %2" : "=v"(pb0) : "v"(p_[su][rb+4]), "v"(p_[su][rb+5]));
            asm("v_cvt_pk_bf16_f32 %0, %1, %2" : "=v"(pb1) : "v"(p_[su][rb+6]), "v"(p_[su][rb+7]));
            unsigned sa0 = __shfl_xor(pa0, 32);
            unsigned sa1 = __shfl_xor(pa1, 32);
            unsigned sb0 = __shfl_xor(pb0, 32);
            unsigned sb1 = __shfl_xor(pb1, 32);
            union { unsigned u[4]; short8 s8; } pa;
            pa.u[0] = hi ? sb0 : pa0;   // keys kc*16 + hi*8 + {0,1}
            pa.u[1] = hi ? sb1 : pa1;   // {2,3}
            pa.u[2] = hi ? pb0 : sa0;   // {4,5}
            pa.u[3] = hi ? pb1 : sa1;   // {6,7}
#pragma unroll
            for (int dt = 0; dt < 4; ++dt) {
                int drow = dt * 32 + l31;
                short8 bf = *reinterpret_cast<const short8*>(
                    &VT[drow * 64 + (((kc * 2 + hi) ^ (l31 & 7)) << 3)]);
                acc[dt] = __builtin_amdgcn_mfma_f32_32x32x16_bf16(pa.s8, bf, acc[dt], 0, 0, 0);
            }
        }
    }

    // ---- epilogue: scale by w/l (per acc row, via LDS) and accumulate ----
    float linv = 1.f / l_run;
    int widx = (phase == 0) ? 2 : 1;
    wfac[wv][l31] = w[(size_t)t * (H_ * 3) + h * 3 + widx] * linv;
    __syncthreads();
    float wfr[16];
#pragma unroll
    for (int r = 0; r < 16; ++r)
        wfr[r] = wfac[wv][(r & 3) + 8 * (r >> 2) + hi4];
#pragma unroll
    for (int dt = 0; dt < 4; ++dt)
#pragma unroll
        for (int r = 0; r < 16; ++r) {
            int crow = (r & 3) + 8 * (r >> 2) + hi4;
            int tt = t0 + (crow & 15);
            int hh = kh * G_ + 2 * wv + (crow >> 4);
            atomicAdd(&out[(size_t)tt * (H_ * D_) + hh * D_ + dt * 32 + l31],
                      acc[dt][r] * wfr[r]);
        }
}

// ---------------- launch ----------------
extern "C" void kernel_launch(void* const* d_in, const int* in_sizes, int n_in,
                              void* d_out, int out_size, void* d_ws, size_t ws_size,
                              hipStream_t stream) {
    const float* q = (const float*)d_in[0];
    const float* k = (const float*)d_in[1];
    const float* v = (const float*)d_in[2];
    const float* w = (const float*)d_in[3];
    float* out = (float*)d_out;

    float* cmpk = (float*)d_ws;
    float* cmpv = cmpk + KH_ * NCMP * D_;
    unsigned int* sel = (unsigned int*)(cmpv + KH_ * NCMP * D_);

    hipLaunchKernelGGL(build_cmp, dim3(KH_ * NCMP), dim3(128), 0, stream, k, v, cmpk, cmpv);
    hipLaunchKernelGGL(cmp_attn_select, dim3(T_ * KH_), dim3(256), 0, stream,
                       q, w, cmpk, cmpv, out, sel);
    hipLaunchKernelGGL(slc_win_mfma, dim3(T_ / 16, KH_, 2), dim3(256), 0, stream,
                       q, k, v, w, sel, out);
}

// Round 4
// 410.251 us; speedup vs baseline: 2.6366x; 1.1253x over previous
//
#include <hip/hip_runtime.h>
#include <hip/hip_bf16.h>
#include <math.h>

#define T_ 2048
#define H_ 16
#define KH_ 2
#define G_ 8
#define D_ 128
#define NCMP 127
#define NBLK 32
#define TOPN 16
#define WIN_ 512
#define SCALE 0.08838834764831845f

typedef __attribute__((ext_vector_type(8))) short short8;
typedef __attribute__((ext_vector_type(16))) float f32x16;

__device__ __forceinline__ unsigned short f2bf(float x) {
    union { float f; unsigned u; } c; c.f = x;
    unsigned u = c.u + 0x7fffu + ((c.u >> 16) & 1u);
    return (unsigned short)(u >> 16);
}

// ---------------- kernel 1: build compressed (mean-pooled) K/V ----------------
__global__ void build_cmp(const float* __restrict__ k, const float* __restrict__ v,
                          float* __restrict__ cmpk, float* __restrict__ cmpv) {
    int j  = blockIdx.x % NCMP;
    int kh = blockIdx.x / NCMP;
    int d  = threadIdx.x;
    int s0 = j * 16;
    float sk = 0.f, sv = 0.f;
    for (int i = 0; i < 32; ++i) {
        sk += k[(size_t)(s0 + i) * KH_ * D_ + kh * D_ + d];
        sv += v[(size_t)(s0 + i) * KH_ * D_ + kh * D_ + d];
    }
    cmpk[(kh * NCMP + j) * D_ + d] = sk * (1.f / 32.f);
    cmpv[(kh * NCMP + j) * D_ + d] = sv * (1.f / 32.f);
}

// ---------------- kernel 2: compressed attention + top-16 block selection ----
// fp32 exact (selection is discrete). LDS-tiled: cmpk/cmpv staged per tile,
// register-blocked so each staged value is read once per thread.
__global__ __launch_bounds__(256) void cmp_attn_select(
        const float* __restrict__ q, const float* __restrict__ w,
        const float* __restrict__ cmpk, const float* __restrict__ cmpv,
        float* __restrict__ out, unsigned int* __restrict__ sel) {
    int bid = blockIdx.x;
    int kh  = bid & 1;
    int t   = bid >> 1;
    int tid = threadIdx.x;

    __shared__ float qs[G_][D_];
    __shared__ float ls[G_][128];
    __shared__ float tile[32 * 132];    // j-tile staging (pad 132 -> 16B-aligned rows)
    __shared__ float wsc[NCMP];
    __shared__ float bsc[NBLK];

    for (int i = tid; i < G_ * D_; i += 256)
        qs[i >> 7][i & 127] = q[(size_t)t * H_ * D_ + (kh * G_ + (i >> 7)) * D_ + (i & 127)];

    int nv = (t >= 31) ? (((t - 31) >> 4) + 1) : 0;
    if (nv > NCMP) nv = NCMP;

    // ---- logits: 4 tiles of 32 j. thread = (jl = tid>>3, c = tid&7 d-chunk) ----
    const int jl = tid >> 3;
    const int c  = tid & 7;
    for (int jt = 0; jt < 4; ++jt) {
        __syncthreads();
#pragma unroll
        for (int it = 0; it < 4; ++it) {
            int f4 = it * 1024 + tid * 4;
            int r = f4 >> 7, d = f4 & 127;
            int j = jt * 32 + r;
            float4 val = make_float4(0.f, 0.f, 0.f, 0.f);
            if (j < NCMP) val = *reinterpret_cast<const float4*>(
                    &cmpk[(size_t)(kh * NCMP + j) * D_ + d]);
            *reinterpret_cast<float4*>(&tile[r * 132 + d]) = val;
        }
        __syncthreads();
        float part[G_];
#pragma unroll
        for (int g = 0; g < G_; ++g) part[g] = 0.f;
#pragma unroll
        for (int dd = 0; dd < 4; ++dd) {
            float4 kv = *reinterpret_cast<const float4*>(&tile[jl * 132 + c * 16 + dd * 4]);
#pragma unroll
            for (int g = 0; g < G_; ++g) {
                float4 qv = *reinterpret_cast<const float4*>(&qs[g][c * 16 + dd * 4]);
                part[g] += qv.x * kv.x + qv.y * kv.y + qv.z * kv.z + qv.w * kv.w;
            }
        }
#pragma unroll
        for (int g = 0; g < G_; ++g) {
            part[g] += __shfl_xor(part[g], 1);
            part[g] += __shfl_xor(part[g], 2);
            part[g] += __shfl_xor(part[g], 4);
        }
        int j = jt * 32 + jl;
        if (c == 0 && j < NCMP) {
#pragma unroll
            for (int g = 0; g < G_; ++g) ls[g][j] = part[g] * SCALE;
        }
    }
    __syncthreads();

    // ---- softmax per head (32-lane subgroup) ----
    {
        int g = tid >> 5, l = tid & 31;
        if (nv > 0) {
            float m = -INFINITY;
            for (int j = l; j < nv; j += 32) m = fmaxf(m, ls[g][j]);
            for (int o = 16; o; o >>= 1) m = fmaxf(m, __shfl_xor(m, o, 32));
            float ssum = 0.f;
            for (int j = l; j < nv; j += 32) {
                float e = expf(ls[g][j] - m);
                ls[g][j] = e;
                ssum += e;
            }
            for (int o = 16; o; o >>= 1) ssum += __shfl_xor(ssum, o, 32);
            float inv = 1.f / ssum;
            for (int j = l; j < 128; j += 32)
                ls[g][j] = (j < nv) ? ls[g][j] * inv : 0.f;
        } else {
            for (int j = l; j < 128; j += 32) ls[g][j] = 0.f;
        }
    }
    __syncthreads();

    // ---- PV: 8 tiles of 16 j. thread = (d4 = tid>>3, jg = tid&7) ----
    const int d4 = tid >> 3;
    const int jg = tid & 7;
    float4 accg[G_];
#pragma unroll
    for (int g = 0; g < G_; ++g) accg[g] = make_float4(0.f, 0.f, 0.f, 0.f);
    for (int vt = 0; vt < 8; ++vt) {
        __syncthreads();
#pragma unroll
        for (int it = 0; it < 2; ++it) {
            int f4 = it * 1024 + tid * 4;
            int r = f4 >> 7, d = f4 & 127;
            int j = vt * 16 + r;
            float4 val = make_float4(0.f, 0.f, 0.f, 0.f);
            if (j < NCMP) val = *reinterpret_cast<const float4*>(
                    &cmpv[(size_t)(kh * NCMP + j) * D_ + d]);
            *reinterpret_cast<float4*>(&tile[r * 132 + d]) = val;
        }
        __syncthreads();
#pragma unroll
        for (int jj = 0; jj < 2; ++jj) {
            int jr = jj * 8 + jg;
            int j  = vt * 16 + jr;
            float4 cv = *reinterpret_cast<const float4*>(&tile[jr * 132 + d4 * 4]);
#pragma unroll
            for (int g = 0; g < G_; ++g) {
                float p = ls[g][j];
                accg[g].x += p * cv.x; accg[g].y += p * cv.y;
                accg[g].z += p * cv.z; accg[g].w += p * cv.w;
            }
        }
    }
#pragma unroll
    for (int g = 0; g < G_; ++g) {
        accg[g].x += __shfl_xor(accg[g].x, 1); accg[g].x += __shfl_xor(accg[g].x, 2); accg[g].x += __shfl_xor(accg[g].x, 4);
        accg[g].y += __shfl_xor(accg[g].y, 1); accg[g].y += __shfl_xor(accg[g].y, 2); accg[g].y += __shfl_xor(accg[g].y, 4);
        accg[g].z += __shfl_xor(accg[g].z, 1); accg[g].z += __shfl_xor(accg[g].z, 2); accg[g].z += __shfl_xor(accg[g].z, 4);
        accg[g].w += __shfl_xor(accg[g].w, 1); accg[g].w += __shfl_xor(accg[g].w, 2); accg[g].w += __shfl_xor(accg[g].w, 4);
    }
    if (jg == 0) {
#pragma unroll
        for (int g = 0; g < G_; ++g) {
            int h = kh * G_ + g;
            float w0 = w[(size_t)t * (H_ * 3) + h * 3 + 0];
            float4 o;
            o.x = w0 * accg[g].x; o.y = w0 * accg[g].y;
            o.z = w0 * accg[g].z; o.w = w0 * accg[g].w;
            *reinterpret_cast<float4*>(&out[(size_t)t * H_ * D_ + h * D_ + d4 * 4]) = o;
        }
    }
    __syncthreads();

    // ---- block scores + stable top-16 (unchanged, fp32 exact) ----
    if (tid < NCMP) {
        float s = 0.f;
        for (int g = 0; g < G_; ++g) s += ls[g][tid];
        wsc[tid] = s;
    }
    __syncthreads();

    if (tid < NBLK) {
        int b = tid;
        float sc = 0.f;
        int j0 = 4 * b - 1; if (j0 < 0) j0 = 0;
        int j1 = 4 * b + 3; if (j1 > NCMP - 1) j1 = NCMP - 1;
        for (int j = j0; j <= j1; ++j) sc += wsc[j];
        int tb = t >> 6;
        bool forced = (b == 0) || (b <= tb && b >= tb - 1);
        if (forced) sc = 1e30f;
        if (b * 64 > t) sc = -1e30f;
        bsc[b] = sc;
    }
    __syncthreads();

    if (tid < 64) {
        bool selbit = false;
        if (tid < NBLK) {
            float sb = bsc[tid];
            int cnt = 0;
            for (int b2 = 0; b2 < NBLK; ++b2) {
                float s2 = bsc[b2];
                cnt += (s2 > sb) || (s2 == sb && b2 < tid);
            }
            selbit = (cnt < TOPN);
        }
        unsigned long long bal = __ballot(selbit);
        if (tid == 0) sel[kh * T_ + t] = (unsigned int)bal;
    }
}

// ---------------- kernel 3: MFMA flash window+selected attention -------------
// grid (T/16, KH, phase). V staged ROW-major bf16 with K's XOR swizzle
// (conflict-free b64 writes); PV B-frags via 8 scalar u16 LDS reads
// (~2-way/broadcast). Output: scratch buffers (plain stores, exclusive
// ownership per phase) or atomicAdd fallback if ws too small.
__global__ __launch_bounds__(256, 2) void slc_win_mfma(
        const float* __restrict__ q, const float* __restrict__ k,
        const float* __restrict__ v, const float* __restrict__ w,
        const unsigned int* __restrict__ sel, float* __restrict__ out,
        float* __restrict__ winb, float* __restrict__ slcb, int use_scratch) {
    const int qt    = blockIdx.x;
    const int kh    = blockIdx.y;
    const int phase = blockIdx.z;
    const int t0    = qt * 16;
    const int tid   = threadIdx.x;
    const int wv    = tid >> 6;
    const int lane  = tid & 63;
    const int l31   = lane & 31;
    const int hi    = lane >> 5;
    const int hi4   = hi * 4;

    __shared__ unsigned short Kl[64 * 128];   // bf16, XOR-swizzled [key][d]
    __shared__ unsigned short Vl[64 * 128];   // bf16, XOR-swizzled [key][d] (row-major!)
    __shared__ float wfac[4][32];

    const int qloc = l31 & 15;
    const int t    = t0 + qloc;
    const int hloc = 2 * wv + (l31 >> 4);
    const int h    = kh * G_ + hloc;

    // Q fragments (B-operand): lane holds Q[row=l31][d = dc*16 + hi*8 + j]
    short8 qf[8];
    {
        const float* qrow = q + (size_t)t * (H_ * D_) + h * D_;
#pragma unroll
        for (int dc = 0; dc < 8; ++dc) {
            int d0 = dc * 16 + hi * 8;
            float4 x = *reinterpret_cast<const float4*>(qrow + d0);
            float4 y = *reinterpret_cast<const float4*>(qrow + d0 + 4);
            short8 f;
            f[0] = (short)f2bf(x.x); f[1] = (short)f2bf(x.y);
            f[2] = (short)f2bf(x.z); f[3] = (short)f2bf(x.w);
            f[4] = (short)f2bf(y.x); f[5] = (short)f2bf(y.y);
            f[6] = (short)f2bf(y.z); f[7] = (short)f2bf(y.w);
            qf[dc] = f;
        }
    }

    const unsigned int smask = sel[kh * T_ + t];
    const int tbmax = t0 >> 6;
    unsigned int um = 0;
    int b0 = 0;
    if (phase == 0) {
        int lo = t0 - (WIN_ - 1); if (lo < 0) lo = 0;
        b0 = lo >> 6;
    } else {
        unsigned int vm = (tbmax >= 31) ? 0xffffffffu : ((2u << tbmax) - 1u);
        um = smask;
        um |= __shfl_xor(um, 1); um |= __shfl_xor(um, 2);
        um |= __shfl_xor(um, 4); um |= __shfl_xor(um, 8);
        um &= vm;
    }

    f32x16 acc[4];
#pragma unroll
    for (int dt = 0; dt < 4; ++dt)
#pragma unroll
        for (int r = 0; r < 16; ++r) acc[dt][r] = 0.f;
    float m_run = -1e30f, l_run = 0.f;

    int bidx = b0;
    unsigned int rem = um;
    while (true) {
        int b;
        if (phase == 0) { if (bidx > tbmax) break; b = bidx++; }
        else            { if (!rem) break; b = __ffs(rem) - 1; rem &= rem - 1; }
        const int s0 = b << 6;

        __syncthreads();
        // ---- stage K and V (both row-major bf16, XOR-swizzled 16B chunks) ----
#pragma unroll
        for (int it = 0; it < 8; ++it) {
            int i = tid + it * 256;
            int r = i >> 5, c4 = i & 31;
            int swzoff = (((c4 >> 1) ^ (r & 7)) << 3) + (c4 & 1) * 4;
            const float* kp = k + (size_t)(s0 + r) * (KH_ * D_) + kh * D_ + c4 * 4;
            float4 kx = *reinterpret_cast<const float4*>(kp);
            ushort4 kb;
            kb.x = f2bf(kx.x); kb.y = f2bf(kx.y); kb.z = f2bf(kx.z); kb.w = f2bf(kx.w);
            *reinterpret_cast<ushort4*>(&Kl[r * 128 + swzoff]) = kb;
            const float* vp = v + (size_t)(s0 + r) * (KH_ * D_) + kh * D_ + c4 * 4;
            float4 vx = *reinterpret_cast<const float4*>(vp);
            ushort4 vb;
            vb.x = f2bf(vx.x); vb.y = f2bf(vx.y); vb.z = f2bf(vx.z); vb.w = f2bf(vx.w);
            *reinterpret_cast<ushort4*>(&Vl[r * 128 + swzoff]) = vb;
        }
        __syncthreads();

        // ---- QK^T (swapped): S^T[key][combo] ----
        f32x16 s_[2];
#pragma unroll
        for (int r = 0; r < 16; ++r) { s_[0][r] = 0.f; s_[1][r] = 0.f; }
#pragma unroll
        for (int dc = 0; dc < 8; ++dc) {
            int c8 = dc * 2 + hi;
            short8 a0 = *reinterpret_cast<const short8*>(
                &Kl[l31 * 128 + ((c8 ^ (l31 & 7)) << 3)]);
            short8 a1 = *reinterpret_cast<const short8*>(
                &Kl[(32 + l31) * 128 + ((c8 ^ (l31 & 7)) << 3)]);
            s_[0] = __builtin_amdgcn_mfma_f32_32x32x16_bf16(a0, qf[dc], s_[0], 0, 0, 0);
            s_[1] = __builtin_amdgcn_mfma_f32_32x32x16_bf16(a1, qf[dc], s_[1], 0, 0, 0);
        }

        // ---- mask + online softmax (wave-uniform max; see round-3 note) ----
        const int sb = (smask >> b) & 1;
        float p_[2][16];
        float mc = -INFINITY;
#pragma unroll
        for (int sub = 0; sub < 2; ++sub)
#pragma unroll
            for (int r = 0; r < 16; ++r) {
                int crow = (r & 3) + 8 * (r >> 2) + hi4;
                int s = s0 + sub * 32 + crow;
                bool ok = (s <= t) && (phase ? (sb != 0) : (s + WIN_ > t));
                float lg = ok ? s_[sub][r] * SCALE : -INFINITY;
                p_[sub][r] = lg;
                mc = fmaxf(mc, lg);
            }
        mc = fmaxf(mc, __shfl_xor(mc, 1));
        mc = fmaxf(mc, __shfl_xor(mc, 2));
        mc = fmaxf(mc, __shfl_xor(mc, 4));
        mc = fmaxf(mc, __shfl_xor(mc, 8));
        mc = fmaxf(mc, __shfl_xor(mc, 16));
        mc = fmaxf(mc, __shfl_xor(mc, 32));
        float mnew = fmaxf(m_run, mc);
        float f = __expf(m_run - mnew);
        float lsum = 0.f;
#pragma unroll
        for (int sub = 0; sub < 2; ++sub)
#pragma unroll
            for (int r = 0; r < 16; ++r) {
                float e = __expf(p_[sub][r] - mnew);
                p_[sub][r] = e;
                lsum += e;
            }
        lsum += __shfl_xor(lsum, 32);   // per-combo row sum
        l_run = l_run * f + lsum;
        m_run = mnew;
#pragma unroll
        for (int dt = 0; dt < 4; ++dt)
#pragma unroll
            for (int r = 0; r < 16; ++r) acc[dt][r] *= f;

        // ---- P -> bf16 A-fragments, PV (B-frag = 8 scalar reads of V col) ----
#pragma unroll
        for (int kc = 0; kc < 4; ++kc) {
            const int su = kc >> 1, rb = (kc & 1) * 8;
            unsigned pa0, pb0, pa1, pb1;
            asm("v_cvt_pk_bf16_f32 %0, %1, %2" : "=v"(pa0) : "v"(p_[su][rb+0]), "v"(p_[su][rb+1]));
            asm("v_cvt_pk_bf16_f32 %0, %1, %2" : "=v"(pa1) : "v"(p_[su][rb+2]), "v"(p_[su][rb+3]));
            asm("v_cvt_pk_bf16_f32 %0, %1, %2" : "=v"(pb0) : "v"(p_[su][rb+4]), "v"(p_[su][rb+5]));
            asm("v_cvt_pk_bf16_f32 %0, %1, %2" : "=v"(pb1) : "v"(p_[su][rb+6]), "v"(p_[su][rb+7]));
            unsigned sa0 = __shfl_xor(pa0, 32);
            unsigned sa1 = __shfl_xor(pa1, 32);
            unsigned sb0 = __shfl_xor(pb0, 32);
            unsigned sb1 = __shfl_xor(pb1, 32);
            union { unsigned u[4]; short8 s8; } pa;
            pa.u[0] = hi ? sb0 : pa0;
            pa.u[1] = hi ? sb1 : pa1;
            pa.u[2] = hi ? pb0 : sa0;
            pa.u[3] = hi ? pb1 : sa1;
            const int kb = kc * 16 + hi * 8;   // kb % 8 == 0 -> (kb+e)&7 == e
#pragma unroll
            for (int dt = 0; dt < 4; ++dt) {
                int d = dt * 32 + l31;
                int dhi = d >> 3, dlo = d & 7;
                union { unsigned short u[8]; short8 s8; } bf;
#pragma unroll
                for (int e = 0; e < 8; ++e)
                    bf.u[e] = Vl[(kb + e) * 128 + ((dhi ^ e) << 3) + dlo];
                acc[dt] = __builtin_amdgcn_mfma_f32_32x32x16_bf16(pa.s8, bf.s8, acc[dt], 0, 0, 0);
            }
        }
    }

    // ---- epilogue ----
    float linv = 1.f / l_run;
    int widx = (phase == 0) ? 2 : 1;
    wfac[wv][l31] = w[(size_t)t * (H_ * 3) + h * 3 + widx] * linv;
    __syncthreads();
    float wfr[16];
#pragma unroll
    for (int r = 0; r < 16; ++r)
        wfr[r] = wfac[wv][(r & 3) + 8 * (r >> 2) + hi4];
    float* base = (phase == 0) ? winb : slcb;
#pragma unroll
    for (int dt = 0; dt < 4; ++dt)
#pragma unroll
        for (int r = 0; r < 16; ++r) {
            int crow = (r & 3) + 8 * (r >> 2) + hi4;
            int tt = t0 + (crow & 15);
            int hh = kh * G_ + 2 * wv + (crow >> 4);
            size_t idx = (size_t)tt * (H_ * D_) + hh * D_ + dt * 32 + l31;
            float val = acc[dt][r] * wfr[r];
            if (use_scratch) base[idx] = val;
            else             atomicAdd(&out[idx], val);
        }
}

// ---------------- kernel 4: combine (scratch mode only) ----------------------
__global__ __launch_bounds__(256) void combine_out(float* __restrict__ out,
        const float* __restrict__ a, const float* __restrict__ b) {
    int i = blockIdx.x * 256 + threadIdx.x;
    float4 o = reinterpret_cast<float4*>(out)[i];
    float4 x = reinterpret_cast<const float4*>(a)[i];
    float4 y = reinterpret_cast<const float4*>(b)[i];
    o.x += x.x + y.x; o.y += x.y + y.y; o.z += x.z + y.z; o.w += x.w + y.w;
    reinterpret_cast<float4*>(out)[i] = o;
}

// ---------------- launch ----------------
extern "C" void kernel_launch(void* const* d_in, const int* in_sizes, int n_in,
                              void* d_out, int out_size, void* d_ws, size_t ws_size,
                              hipStream_t stream) {
    const float* q = (const float*)d_in[0];
    const float* k = (const float*)d_in[1];
    const float* v = (const float*)d_in[2];
    const float* w = (const float*)d_in[3];
    float* out = (float*)d_out;

    float* ws = (float*)d_ws;
    const size_t f_cmpk = 0;
    const size_t f_cmpv = (size_t)KH_ * NCMP * D_;            // 32512
    const size_t f_sel  = 2 * (size_t)KH_ * NCMP * D_;        // 65024
    const size_t f_win  = f_sel + 4096;                       // sel: 4096 u32
    const size_t f_slc  = f_win + (size_t)T_ * H_ * D_;
    const size_t f_end  = f_slc + (size_t)T_ * H_ * D_;
    const int use_scratch = (ws_size >= f_end * sizeof(float)) ? 1 : 0;

    float* cmpk = ws + f_cmpk;
    float* cmpv = ws + f_cmpv;
    unsigned int* sel = (unsigned int*)(ws + f_sel);
    float* winb = use_scratch ? (ws + f_win) : out;
    float* slcb = use_scratch ? (ws + f_slc) : out;

    hipLaunchKernelGGL(build_cmp, dim3(KH_ * NCMP), dim3(128), 0, stream, k, v, cmpk, cmpv);
    hipLaunchKernelGGL(cmp_attn_select, dim3(T_ * KH_), dim3(256), 0, stream,
                       q, w, cmpk, cmpv, out, sel);
    hipLaunchKernelGGL(slc_win_mfma, dim3(T_ / 16, KH_, 2), dim3(256), 0, stream,
                       q, k, v, w, sel, out, winb, slcb, use_scratch);
    if (use_scratch) {
        hipLaunchKernelGGL(combine_out, dim3((T_ * H_ * D_ / 4) / 256), dim3(256), 0, stream,
                           out, winb, slcb);
    }
}

// Round 5
// 291.618 us; speedup vs baseline: 3.7092x; 1.4068x over previous
//
#include <hip/hip_runtime.h>
#include <hip/hip_bf16.h>
#include <math.h>

#define T_ 2048
#define H_ 16
#define KH_ 2
#define G_ 8
#define D_ 128
#define NCMP 127
#define JP 128          // padded window count (row 127 zeroed)
#define NBLK 32
#define TOPN 16
#define WIN_ 512
#define SCALE 0.08838834764831845f

typedef __attribute__((ext_vector_type(8))) short short8;
typedef __attribute__((ext_vector_type(16))) float f32x16;

__device__ __forceinline__ unsigned short f2bf(float x) {
    union { float f; unsigned u; } c; c.f = x;
    unsigned u = c.u + 0x7fffu + ((c.u >> 16) & 1u);
    return (unsigned short)(u >> 16);
}
__device__ __forceinline__ float bf2f(unsigned short b) {
    union { unsigned u; float f; } c; c.u = (unsigned)b << 16; return c.f;
}

// ---------------- kernel 1: compressed K/V means -> bf16 hi/lo + v bf16 ------
// grid KH_*128 blocks x 128 thr. Row j=127 zero-padded.
__global__ __launch_bounds__(128) void build_cmp(
        const float* __restrict__ k, const float* __restrict__ v,
        unsigned short* __restrict__ khi, unsigned short* __restrict__ klo,
        unsigned short* __restrict__ vbf) {
    int j  = blockIdx.x & 127;
    int kh = blockIdx.x >> 7;
    int d  = threadIdx.x;
    size_t o = ((size_t)kh * JP + j) * D_ + d;
    if (j >= NCMP) { khi[o] = 0; klo[o] = 0; vbf[o] = 0; return; }
    int s0 = j * 16;
    float sk = 0.f, sv = 0.f;
    for (int i = 0; i < 32; ++i) {
        sk += k[(size_t)(s0 + i) * KH_ * D_ + kh * D_ + d];
        sv += v[(size_t)(s0 + i) * KH_ * D_ + kh * D_ + d];
    }
    float mk = sk * (1.f / 32.f), mv = sv * (1.f / 32.f);
    unsigned short hb = f2bf(mk);
    khi[o] = hb;
    klo[o] = f2bf(mk - bf2f(hb));   // residual: khi+klo ~ fp32-accurate
    vbf[o] = f2bf(mv);
}

// ---------------- kernel 2: MFMA compressed attention + top-16 selection -----
// grid (T/16, KH), 256 thr = 4 waves. Wave wv owns combos = 16 q x g {2wv,2wv+1}.
// Swapped QK with split-bf16 (khi*qhi + klo*qhi + khi*qlo) -> fp32-grade logits
// so the discrete top-k matches numpy. Softmax fp32 per-lane; PV bf16 MFMA.
__global__ __launch_bounds__(256, 1) void cmp_attn_mfma(
        const float* __restrict__ q, const float* __restrict__ w,
        const unsigned short* __restrict__ khi_g, const unsigned short* __restrict__ klo_g,
        const unsigned short* __restrict__ vb_g,
        float* __restrict__ out, unsigned int* __restrict__ sel) {
    const int qt  = blockIdx.x;
    const int kh  = blockIdx.y;
    const int t0  = qt * 16;
    const int tid = threadIdx.x;
    const int wv  = tid >> 6;
    const int lane = tid & 63;
    const int l31 = lane & 31;
    const int hi  = lane >> 5;
    const int hi4 = hi * 4;

    __shared__ unsigned short KHI[JP * D_];   // 32 KB, XOR-swizzled 16B chunks
    __shared__ unsigned short KLO[JP * D_];   // 32 KB
    __shared__ unsigned short VB[JP * D_];    // 32 KB
    __shared__ float wsc_s[16 * 132];         // per-q window scores (stride 132)
    __shared__ float bsc_s[16 * 32];
    __shared__ unsigned int sel_s[16];
    __shared__ float wfac[4][32];

    if (tid < 16) sel_s[tid] = 0u;
    for (int i = tid; i < 16 * 132; i += 256) wsc_s[i] = 0.f;

    // ---- stage khi/klo/vb: lane->(r,c) map with (c^(r&7)) swizzle ----
    // per instr: bank group = (c^(r&7))&7 = (lane&7)^(lane>>3) -> balanced, conflict-free
#pragma unroll
    for (int bfi = 0; bfi < 3; ++bfi) {
        const unsigned short* src = (bfi == 0) ? khi_g : (bfi == 1) ? klo_g : vb_g;
        unsigned short* dst = (bfi == 0) ? KHI : (bfi == 1) ? KLO : VB;
        src += (size_t)kh * JP * D_;
#pragma unroll
        for (int it = 0; it < 8; ++it) {
            int kk = it * 4 + wv;           // 0..31
            int r  = (lane >> 3) + 8 * (kk >> 1);
            int c  = (lane & 7) + 8 * (kk & 1);
            uint4 val = *reinterpret_cast<const uint4*>(src + r * D_ + c * 8);
            *reinterpret_cast<uint4*>(&dst[r * D_ + ((c ^ (r & 7)) << 3)]) = val;
        }
    }

    // ---- Q hi/lo fragments (B-operand): lane = combo l31, d = dc*16+hi*8+j ----
    const int qloc = l31 & 15;
    const int t    = t0 + qloc;
    const int h    = kh * G_ + 2 * wv + (l31 >> 4);
    short8 qhi[8], qlo[8];
    {
        const float* qrow = q + (size_t)t * (H_ * D_) + h * D_;
#pragma unroll
        for (int dc = 0; dc < 8; ++dc) {
            int d0 = dc * 16 + hi * 8;
            float4 x = *reinterpret_cast<const float4*>(qrow + d0);
            float4 y = *reinterpret_cast<const float4*>(qrow + d0 + 4);
            float e_[8] = {x.x, x.y, x.z, x.w, y.x, y.y, y.z, y.w};
            short8 fh, fl;
#pragma unroll
            for (int e = 0; e < 8; ++e) {
                unsigned short hb = f2bf(e_[e]);
                fh[e] = (short)hb;
                fl[e] = (short)f2bf(e_[e] - bf2f(hb));
            }
            qhi[dc] = fh; qlo[dc] = fl;
        }
    }
    __syncthreads();

    // ---- QK^T split-bf16: S^T[j][combo], lane owns combo column l31 ----
    f32x16 s_[4];
#pragma unroll
    for (int tl = 0; tl < 4; ++tl)
#pragma unroll
        for (int r = 0; r < 16; ++r) s_[tl][r] = 0.f;
#pragma unroll
    for (int tl = 0; tl < 4; ++tl) {
        int rbase = tl * 32 + l31;
#pragma unroll
        for (int dc = 0; dc < 8; ++dc) {
            int off = rbase * D_ + (((dc * 2 + hi) ^ (l31 & 7)) << 3);
            short8 ahi = *reinterpret_cast<const short8*>(&KHI[off]);
            short8 alo = *reinterpret_cast<const short8*>(&KLO[off]);
            s_[tl] = __builtin_amdgcn_mfma_f32_32x32x16_bf16(ahi, qhi[dc], s_[tl], 0, 0, 0);
            s_[tl] = __builtin_amdgcn_mfma_f32_32x32x16_bf16(alo, qhi[dc], s_[tl], 0, 0, 0);
            s_[tl] = __builtin_amdgcn_mfma_f32_32x32x16_bf16(ahi, qlo[dc], s_[tl], 0, 0, 0);
        }
    }

    // ---- mask + softmax (fp32, per-lane rows; partner lane holds other rows) ----
    const int nv = (t >= 31) ? (((t - 31) >> 4) + 1) : 0;
    float m = -1e30f;
#pragma unroll
    for (int tl = 0; tl < 4; ++tl)
#pragma unroll
        for (int r = 0; r < 16; ++r) {
            int j = tl * 32 + (r & 3) + 8 * (r >> 2) + hi4;
            float lg = (j < nv) ? s_[tl][r] * SCALE : -1e30f;
            s_[tl][r] = lg;
            m = fmaxf(m, lg);
        }
    m = fmaxf(m, __shfl_xor(m, 32));
    float lsum = 0.f;
#pragma unroll
    for (int tl = 0; tl < 4; ++tl)
#pragma unroll
        for (int r = 0; r < 16; ++r) {
            float e = __expf(s_[tl][r] - m);   // nv==0 -> e=1 but linv=0 kills it
            s_[tl][r] = e;
            lsum += e;
        }
    lsum += __shfl_xor(lsum, 32);
    const float linv = (nv > 0) ? 1.f / lsum : 0.f;

    // ---- window scores: wsc[q][j] += p (summed over g via LDS atomics) ----
#pragma unroll
    for (int tl = 0; tl < 4; ++tl)
#pragma unroll
        for (int r = 0; r < 16; ++r) {
            int j = tl * 32 + (r & 3) + 8 * (r >> 2) + hi4;
            atomicAdd(&wsc_s[qloc * 132 + j], s_[tl][r] * linv);
        }

    // ---- PV: P~ -> bf16 A-frags (cvt_pk + partner shfl), V B-frags from LDS ----
    f32x16 acc[4];
#pragma unroll
    for (int dt = 0; dt < 4; ++dt)
#pragma unroll
        for (int r = 0; r < 16; ++r) acc[dt][r] = 0.f;
#pragma unroll
    for (int kc = 0; kc < 8; ++kc) {
        const int su = kc >> 1, rb = (kc & 1) * 8;
        unsigned pa0, pa1, pb0, pb1;
        asm("v_cvt_pk_bf16_f32 %0, %1, %2" : "=v"(pa0) : "v"(s_[su][rb+0]), "v"(s_[su][rb+1]));
        asm("v_cvt_pk_bf16_f32 %0, %1, %2" : "=v"(pa1) : "v"(s_[su][rb+2]), "v"(s_[su][rb+3]));
        asm("v_cvt_pk_bf16_f32 %0, %1, %2" : "=v"(pb0) : "v"(s_[su][rb+4]), "v"(s_[su][rb+5]));
        asm("v_cvt_pk_bf16_f32 %0, %1, %2" : "=v"(pb1) : "v"(s_[su][rb+6]), "v"(s_[su][rb+7]));
        unsigned sa0 = __shfl_xor(pa0, 32);
        unsigned sa1 = __shfl_xor(pa1, 32);
        unsigned sb0 = __shfl_xor(pb0, 32);
        unsigned sb1 = __shfl_xor(pb1, 32);
        union { unsigned u[4]; short8 s8; } pa;
        pa.u[0] = hi ? sb0 : pa0;
        pa.u[1] = hi ? sb1 : pa1;
        pa.u[2] = hi ? pb0 : sa0;
        pa.u[3] = hi ? pb1 : sa1;
#pragma unroll
        for (int dt = 0; dt < 4; ++dt) {
            int d = dt * 32 + l31;
            int dhi = d >> 3, dlo = d & 7;
            union { unsigned short u[8]; short8 s8; } bf;
#pragma unroll
            for (int e = 0; e < 8; ++e)
                bf.u[e] = VB[(kc * 16 + hi * 8 + e) * D_ + ((dhi ^ e) << 3) + dlo];
            acc[dt] = __builtin_amdgcn_mfma_f32_32x32x16_bf16(pa.s8, bf.s8, acc[dt], 0, 0, 0);
        }
    }

    // ---- epilogue prep + sync (wfac + wsc consumers below) ----
    wfac[wv][l31] = w[(size_t)t * (H_ * 3) + h * 3 + 0] * linv;
    __syncthreads();

    // o_cmp write (exclusive ownership; overwrites poison)
    float wfr[16];
#pragma unroll
    for (int r = 0; r < 16; ++r)
        wfr[r] = wfac[wv][(r & 3) + 8 * (r >> 2) + hi4];
#pragma unroll
    for (int dt = 0; dt < 4; ++dt)
#pragma unroll
        for (int r = 0; r < 16; ++r) {
            int crow = (r & 3) + 8 * (r >> 2) + hi4;
            int tt = t0 + (crow & 15);
            int hh = kh * G_ + 2 * wv + (crow >> 4);
            out[(size_t)tt * (H_ * D_) + hh * D_ + dt * 32 + l31] = acc[dt][r] * wfr[r];
        }

    // block scores: thread = (q = tid>>4, b in {tid&15, tid&15+16})
#pragma unroll
    for (int half = 0; half < 2; ++half) {
        int b  = (tid & 15) + half * 16;
        int qq = tid >> 4;
        int tt = t0 + qq;
        float sc = 0.f;
        int j0 = 4 * b - 1; if (j0 < 0) j0 = 0;
        int j1 = 4 * b + 3; if (j1 > NCMP - 1) j1 = NCMP - 1;
        for (int j = j0; j <= j1; ++j) sc += wsc_s[qq * 132 + j];
        int tb = tt >> 6;
        bool forced = (b == 0) || (b <= tb && b >= tb - 1);
        if (forced) sc = 1e30f;
        if (b * 64 > tt) sc = -1e30f;
        bsc_s[qq * 32 + b] = sc;
    }
    __syncthreads();

    // stable top-16 rank count (matches jax.lax.top_k tie-break)
#pragma unroll
    for (int half = 0; half < 2; ++half) {
        int b  = (tid & 15) + half * 16;
        int qq = tid >> 4;
        float sb = bsc_s[qq * 32 + b];
        int cnt = 0;
        for (int b2 = 0; b2 < NBLK; ++b2) {
            float s2 = bsc_s[qq * 32 + b2];
            cnt += (s2 > sb) || (s2 == sb && b2 < b);
        }
        if (cnt < TOPN) atomicOr(&sel_s[qq], 1u << b);
    }
    __syncthreads();
    if (tid < 16) sel[kh * T_ + t0 + tid] = sel_s[tid];
}

// ---------------- kernel 3: MFMA flash window+selected attention -------------
// (unchanged from round 4)
__global__ __launch_bounds__(256, 2) void slc_win_mfma(
        const float* __restrict__ q, const float* __restrict__ k,
        const float* __restrict__ v, const float* __restrict__ w,
        const unsigned int* __restrict__ sel, float* __restrict__ out,
        float* __restrict__ winb, float* __restrict__ slcb, int use_scratch) {
    const int qt    = blockIdx.x;
    const int kh    = blockIdx.y;
    const int phase = blockIdx.z;
    const int t0    = qt * 16;
    const int tid   = threadIdx.x;
    const int wv    = tid >> 6;
    const int lane  = tid & 63;
    const int l31   = lane & 31;
    const int hi    = lane >> 5;
    const int hi4   = hi * 4;

    __shared__ unsigned short Kl[64 * 128];
    __shared__ unsigned short Vl[64 * 128];
    __shared__ float wfac[4][32];

    const int qloc = l31 & 15;
    const int t    = t0 + qloc;
    const int hloc = 2 * wv + (l31 >> 4);
    const int h    = kh * G_ + hloc;

    short8 qf[8];
    {
        const float* qrow = q + (size_t)t * (H_ * D_) + h * D_;
#pragma unroll
        for (int dc = 0; dc < 8; ++dc) {
            int d0 = dc * 16 + hi * 8;
            float4 x = *reinterpret_cast<const float4*>(qrow + d0);
            float4 y = *reinterpret_cast<const float4*>(qrow + d0 + 4);
            short8 f;
            f[0] = (short)f2bf(x.x); f[1] = (short)f2bf(x.y);
            f[2] = (short)f2bf(x.z); f[3] = (short)f2bf(x.w);
            f[4] = (short)f2bf(y.x); f[5] = (short)f2bf(y.y);
            f[6] = (short)f2bf(y.z); f[7] = (short)f2bf(y.w);
            qf[dc] = f;
        }
    }

    const unsigned int smask = sel[kh * T_ + t];
    const int tbmax = t0 >> 6;
    unsigned int um = 0;
    int b0 = 0;
    if (phase == 0) {
        int lo = t0 - (WIN_ - 1); if (lo < 0) lo = 0;
        b0 = lo >> 6;
    } else {
        unsigned int vm = (tbmax >= 31) ? 0xffffffffu : ((2u << tbmax) - 1u);
        um = smask;
        um |= __shfl_xor(um, 1); um |= __shfl_xor(um, 2);
        um |= __shfl_xor(um, 4); um |= __shfl_xor(um, 8);
        um &= vm;
    }

    f32x16 acc[4];
#pragma unroll
    for (int dt = 0; dt < 4; ++dt)
#pragma unroll
        for (int r = 0; r < 16; ++r) acc[dt][r] = 0.f;
    float m_run = -1e30f, l_run = 0.f;

    int bidx = b0;
    unsigned int rem = um;
    while (true) {
        int b;
        if (phase == 0) { if (bidx > tbmax) break; b = bidx++; }
        else            { if (!rem) break; b = __ffs(rem) - 1; rem &= rem - 1; }
        const int s0 = b << 6;

        __syncthreads();
#pragma unroll
        for (int it = 0; it < 8; ++it) {
            int i = tid + it * 256;
            int r = i >> 5, c4 = i & 31;
            int swzoff = (((c4 >> 1) ^ (r & 7)) << 3) + (c4 & 1) * 4;
            const float* kp = k + (size_t)(s0 + r) * (KH_ * D_) + kh * D_ + c4 * 4;
            float4 kx = *reinterpret_cast<const float4*>(kp);
            ushort4 kb;
            kb.x = f2bf(kx.x); kb.y = f2bf(kx.y); kb.z = f2bf(kx.z); kb.w = f2bf(kx.w);
            *reinterpret_cast<ushort4*>(&Kl[r * 128 + swzoff]) = kb;
            const float* vp = v + (size_t)(s0 + r) * (KH_ * D_) + kh * D_ + c4 * 4;
            float4 vx = *reinterpret_cast<const float4*>(vp);
            ushort4 vb;
            vb.x = f2bf(vx.x); vb.y = f2bf(vx.y); vb.z = f2bf(vx.z); vb.w = f2bf(vx.w);
            *reinterpret_cast<ushort4*>(&Vl[r * 128 + swzoff]) = vb;
        }
        __syncthreads();

        f32x16 s_[2];
#pragma unroll
        for (int r = 0; r < 16; ++r) { s_[0][r] = 0.f; s_[1][r] = 0.f; }
#pragma unroll
        for (int dc = 0; dc < 8; ++dc) {
            int c8 = dc * 2 + hi;
            short8 a0 = *reinterpret_cast<const short8*>(
                &Kl[l31 * 128 + ((c8 ^ (l31 & 7)) << 3)]);
            short8 a1 = *reinterpret_cast<const short8*>(
                &Kl[(32 + l31) * 128 + ((c8 ^ (l31 & 7)) << 3)]);
            s_[0] = __builtin_amdgcn_mfma_f32_32x32x16_bf16(a0, qf[dc], s_[0], 0, 0, 0);
            s_[1] = __builtin_amdgcn_mfma_f32_32x32x16_bf16(a1, qf[dc], s_[1], 0, 0, 0);
        }

        const int sb = (smask >> b) & 1;
        float p_[2][16];
        float mc = -INFINITY;
#pragma unroll
        for (int sub = 0; sub < 2; ++sub)
#pragma unroll
            for (int r = 0; r < 16; ++r) {
                int crow = (r & 3) + 8 * (r >> 2) + hi4;
                int s = s0 + sub * 32 + crow;
                bool ok = (s <= t) && (phase ? (sb != 0) : (s + WIN_ > t));
                float lg = ok ? s_[sub][r] * SCALE : -INFINITY;
                p_[sub][r] = lg;
                mc = fmaxf(mc, lg);
            }
        mc = fmaxf(mc, __shfl_xor(mc, 1));
        mc = fmaxf(mc, __shfl_xor(mc, 2));
        mc = fmaxf(mc, __shfl_xor(mc, 4));
        mc = fmaxf(mc, __shfl_xor(mc, 8));
        mc = fmaxf(mc, __shfl_xor(mc, 16));
        mc = fmaxf(mc, __shfl_xor(mc, 32));
        float mnew = fmaxf(m_run, mc);
        float f = __expf(m_run - mnew);
        float lsum = 0.f;
#pragma unroll
        for (int sub = 0; sub < 2; ++sub)
#pragma unroll
            for (int r = 0; r < 16; ++r) {
                float e = __expf(p_[sub][r] - mnew);
                p_[sub][r] = e;
                lsum += e;
            }
        lsum += __shfl_xor(lsum, 32);
        l_run = l_run * f + lsum;
        m_run = mnew;
#pragma unroll
        for (int dt = 0; dt < 4; ++dt)
#pragma unroll
            for (int r = 0; r < 16; ++r) acc[dt][r] *= f;

#pragma unroll
        for (int kc = 0; kc < 4; ++kc) {
            const int su = kc >> 1, rb = (kc & 1) * 8;
            unsigned pa0, pb0, pa1, pb1;
            asm("v_cvt_pk_bf16_f32 %0, %1, %2" : "=v"(pa0) : "v"(p_[su][rb+0]), "v"(p_[su][rb+1]));
            asm("v_cvt_pk_bf16_f32 %0, %1, %2" : "=v"(pa1) : "v"(p_[su][rb+2]), "v"(p_[su][rb+3]));
            asm("v_cvt_pk_bf16_f32 %0, %1, %2" : "=v"(pb0) : "v"(p_[su][rb+4]), "v"(p_[su][rb+5]));
            asm("v_cvt_pk_bf16_f32 %0, %1, %2" : "=v"(pb1) : "v"(p_[su][rb+6]), "v"(p_[su][rb+7]));
            unsigned sa0 = __shfl_xor(pa0, 32);
            unsigned sa1 = __shfl_xor(pa1, 32);
            unsigned sb0 = __shfl_xor(pb0, 32);
            unsigned sb1 = __shfl_xor(pb1, 32);
            union { unsigned u[4]; short8 s8; } pa;
            pa.u[0] = hi ? sb0 : pa0;
            pa.u[1] = hi ? sb1 : pa1;
            pa.u[2] = hi ? pb0 : sa0;
            pa.u[3] = hi ? pb1 : sa1;
            const int kb = kc * 16 + hi * 8;
#pragma unroll
            for (int dt = 0; dt < 4; ++dt) {
                int d = dt * 32 + l31;
                int dhi = d >> 3, dlo = d & 7;
                union { unsigned short u[8]; short8 s8; } bf;
#pragma unroll
                for (int e = 0; e < 8; ++e)
                    bf.u[e] = Vl[(kb + e) * 128 + ((dhi ^ e) << 3) + dlo];
                acc[dt] = __builtin_amdgcn_mfma_f32_32x32x16_bf16(pa.s8, bf.s8, acc[dt], 0, 0, 0);
            }
        }
    }

    float linv = 1.f / l_run;
    int widx = (phase == 0) ? 2 : 1;
    wfac[wv][l31] = w[(size_t)t * (H_ * 3) + h * 3 + widx] * linv;
    __syncthreads();
    float wfr[16];
#pragma unroll
    for (int r = 0; r < 16; ++r)
        wfr[r] = wfac[wv][(r & 3) + 8 * (r >> 2) + hi4];
    float* base = (phase == 0) ? winb : slcb;
#pragma unroll
    for (int dt = 0; dt < 4; ++dt)
#pragma unroll
        for (int r = 0; r < 16; ++r) {
            int crow = (r & 3) + 8 * (r >> 2) + hi4;
            int tt = t0 + (crow & 15);
            int hh = kh * G_ + 2 * wv + (crow >> 4);
            size_t idx = (size_t)tt * (H_ * D_) + hh * D_ + dt * 32 + l31;
            float val = acc[dt][r] * wfr[r];
            if (use_scratch) base[idx] = val;
            else             atomicAdd(&out[idx], val);
        }
}

// ---------------- kernel 4: combine (scratch mode only) ----------------------
__global__ __launch_bounds__(256) void combine_out(float* __restrict__ out,
        const float* __restrict__ a, const float* __restrict__ b) {
    int i = blockIdx.x * 256 + threadIdx.x;
    float4 o = reinterpret_cast<float4*>(out)[i];
    float4 x = reinterpret_cast<const float4*>(a)[i];
    float4 y = reinterpret_cast<const float4*>(b)[i];
    o.x += x.x + y.x; o.y += x.y + y.y; o.z += x.z + y.z; o.w += x.w + y.w;
    reinterpret_cast<float4*>(out)[i] = o;
}

// ---------------- launch ----------------
extern "C" void kernel_launch(void* const* d_in, const int* in_sizes, int n_in,
                              void* d_out, int out_size, void* d_ws, size_t ws_size,
                              hipStream_t stream) {
    const float* q = (const float*)d_in[0];
    const float* k = (const float*)d_in[1];
    const float* v = (const float*)d_in[2];
    const float* w = (const float*)d_in[3];
    float* out = (float*)d_out;

    char* ws = (char*)d_ws;
    const size_t BUF = (size_t)KH_ * JP * D_ * sizeof(unsigned short);  // 65536
    unsigned short* khi_g = (unsigned short*)(ws);
    unsigned short* klo_g = (unsigned short*)(ws + BUF);
    unsigned short* vb_g  = (unsigned short*)(ws + 2 * BUF);
    unsigned int*   sel   = (unsigned int*)(ws + 3 * BUF);              // 16 KB
    float* winb_s = (float*)(ws + 3 * BUF + 16384);
    float* slcb_s = winb_s + (size_t)T_ * H_ * D_;
    const size_t need = 3 * BUF + 16384 + 2 * (size_t)T_ * H_ * D_ * sizeof(float);
    const int use_scratch = (ws_size >= need) ? 1 : 0;
    float* winb = use_scratch ? winb_s : out;
    float* slcb = use_scratch ? slcb_s : out;

    hipLaunchKernelGGL(build_cmp, dim3(KH_ * 128), dim3(128), 0, stream,
                       k, v, khi_g, klo_g, vb_g);
    hipLaunchKernelGGL(cmp_attn_mfma, dim3(T_ / 16, KH_), dim3(256), 0, stream,
                       q, w, khi_g, klo_g, vb_g, out, sel);
    hipLaunchKernelGGL(slc_win_mfma, dim3(T_ / 16, KH_, 2), dim3(256), 0, stream,
                       q, k, v, w, sel, out, winb, slcb, use_scratch);
    if (use_scratch) {
        hipLaunchKernelGGL(combine_out, dim3((T_ * H_ * D_ / 4) / 256), dim3(256), 0, stream,
                           out, winb, slcb);
    }
}

// Round 6
// 262.132 us; speedup vs baseline: 4.1264x; 1.1125x over previous
//
#include <hip/hip_runtime.h>
#include <hip/hip_bf16.h>
#include <math.h>

#define T_ 2048
#define H_ 16
#define KH_ 2
#define G_ 8
#define D_ 128
#define NCMP 127
#define JP 128
#define NBLK 32
#define TOPN 16
#define WIN_ 512
#define SCALE 0.08838834764831845f

typedef __attribute__((ext_vector_type(8))) short short8;
typedef __attribute__((ext_vector_type(16))) float f32x16;

__device__ __forceinline__ unsigned short f2bf(float x) {
    union { float f; unsigned u; } c; c.f = x;
    unsigned u = c.u + 0x7fffu + ((c.u >> 16) & 1u);
    return (unsigned short)(u >> 16);
}
__device__ __forceinline__ float bf2f(unsigned short b) {
    union { unsigned u; float f; } c; c.u = (unsigned)b << 16; return c.f;
}

// async 16B global->LDS copy (lane i lands at lds + i*16)
#define GLD16(gsrc, lds) \
    __builtin_amdgcn_global_load_lds( \
        (const __attribute__((address_space(1))) unsigned int*)(gsrc), \
        (__attribute__((address_space(3))) unsigned int*)(lds), 16, 0, 0)

// ---------- kernel 0: K/V -> bf16 LDS-image tiles (K row-major, V transposed) --
// Image layouts (per tile kh,b; all in halves):
//   Kimg [r*128 + ((c ^ ((r>>2)&7))<<3) + e] = K[s0+r][c*8+e]      (r<64,c<16)
//   VTimg[d*64  + ((kc8 ^ ((d>>2)&7))<<3) + e] = V[s0+kc8*8+e][d]  (d<128,kc8<8)
__global__ __launch_bounds__(256) void prep_kv(
        const float* __restrict__ k, const float* __restrict__ v,
        unsigned short* __restrict__ kimg, unsigned short* __restrict__ vtimg) {
    const int b  = blockIdx.x;
    const int kh = blockIdx.y;
    const int s0 = b << 6;
    const int tid = threadIdx.x;
    const size_t tb = ((size_t)kh * 32 + b) * 8192;
#pragma unroll
    for (int it = 0; it < 4; ++it) {
        int idx = it * 256 + tid;
        int r = idx >> 4, c = idx & 15;
        const float* src = k + (size_t)(s0 + r) * (KH_ * D_) + kh * D_ + c * 8;
        float4 x = *reinterpret_cast<const float4*>(src);
        float4 y = *reinterpret_cast<const float4*>(src + 4);
        union { unsigned short u[8]; uint4 q; } o;
        o.u[0] = f2bf(x.x); o.u[1] = f2bf(x.y); o.u[2] = f2bf(x.z); o.u[3] = f2bf(x.w);
        o.u[4] = f2bf(y.x); o.u[5] = f2bf(y.y); o.u[6] = f2bf(y.z); o.u[7] = f2bf(y.w);
        *reinterpret_cast<uint4*>(&kimg[tb + r * 128 + ((c ^ ((r >> 2) & 7)) << 3)]) = o.q;
    }
#pragma unroll
    for (int it = 0; it < 4; ++it) {
        int idx = it * 256 + tid;
        int d = idx & 127, kc8 = idx >> 7;
        union { unsigned short u[8]; uint4 q; } o;
#pragma unroll
        for (int e = 0; e < 8; ++e)
            o.u[e] = f2bf(v[(size_t)(s0 + kc8 * 8 + e) * (KH_ * D_) + kh * D_ + d]);
        *reinterpret_cast<uint4*>(&vtimg[tb + d * 64 + ((kc8 ^ ((d >> 2) & 7)) << 3)]) = o.q;
    }
}

// ---------- kernel 1: compressed means -> khi/klo images + flat v bf16 --------
__global__ __launch_bounds__(128) void build_cmp(
        const float* __restrict__ k, const float* __restrict__ v,
        unsigned short* __restrict__ khiI, unsigned short* __restrict__ kloI,
        unsigned short* __restrict__ vflat) {
    int j  = blockIdx.x;
    int kh = blockIdx.y;
    int d  = threadIdx.x;
    unsigned short hb = 0, lb = 0, vb = 0;
    if (j < NCMP) {
        int s0 = j * 16;
        float sk = 0.f, sv = 0.f;
        for (int i = 0; i < 32; ++i) {
            sk += k[(size_t)(s0 + i) * KH_ * D_ + kh * D_ + d];
            sv += v[(size_t)(s0 + i) * KH_ * D_ + kh * D_ + d];
        }
        float mk = sk * (1.f / 32.f), mv = sv * (1.f / 32.f);
        hb = f2bf(mk);
        lb = f2bf(mk - bf2f(hb));
        vb = f2bf(mv);
    }
    int c = d >> 3;
    size_t ib = (size_t)kh * 16384 + j * 128 + ((c ^ ((j >> 2) & 7)) << 3) + (d & 7);
    khiI[ib] = hb;
    kloI[ib] = lb;
    vflat[(size_t)kh * 16384 + j * 128 + d] = vb;
}

// ---------- kernel 1b: flat cmp-v -> transposed image ------------------------
//   CVTimg[d*128 + ((jc8 ^ ((d>>2)&7))<<3) + e] = cmpv[jc8*8+e][d]  (jc8<16)
__global__ __launch_bounds__(256) void prep_cmp_img(
        const unsigned short* __restrict__ vflat, unsigned short* __restrict__ cvtI) {
    const int kh = blockIdx.x;
    const int tid = threadIdx.x;
#pragma unroll
    for (int it = 0; it < 8; ++it) {
        int idx = it * 256 + tid;
        int d = idx & 127, jc8 = idx >> 7;
        union { unsigned short u[8]; uint4 q; } o;
#pragma unroll
        for (int e = 0; e < 8; ++e)
            o.u[e] = vflat[(size_t)kh * 16384 + (jc8 * 8 + e) * 128 + d];
        *reinterpret_cast<uint4*>(
            &cvtI[(size_t)kh * 16384 + d * 128 + ((jc8 ^ ((d >> 2) & 7)) << 3)]) = o.q;
    }
}

// ---------- kernel 2: MFMA compressed attention + top-16 selection -----------
// Split-bf16 QK (khi*qhi + klo*qhi + khi*qlo) for fp32-grade logits -> top-k
// matches numpy. Staging = pure global_load_lds of prebuilt images.
__global__ __launch_bounds__(256, 1) void cmp_attn_mfma(
        const float* __restrict__ q, const float* __restrict__ w,
        const unsigned short* __restrict__ khiI, const unsigned short* __restrict__ kloI,
        const unsigned short* __restrict__ cvtI,
        float* __restrict__ out, unsigned int* __restrict__ sel) {
    const int qt  = blockIdx.x;
    const int kh  = blockIdx.y;
    const int t0  = qt * 16;
    const int tid = threadIdx.x;
    const int wv  = tid >> 6;
    const int lane = tid & 63;
    const int l31 = lane & 31;
    const int hi  = lane >> 5;
    const int hi4 = hi * 4;

    __shared__ unsigned short KHI[JP * D_];
    __shared__ unsigned short KLO[JP * D_];
    __shared__ unsigned short CVT[JP * D_];
    __shared__ float wsc_s[16 * 132];
    __shared__ float bsc_s[16 * 32];
    __shared__ unsigned int sel_s[16];
    __shared__ float wfac[4][32];

    if (tid < 16) sel_s[tid] = 0u;
    for (int i = tid; i < 16 * 132; i += 256) wsc_s[i] = 0.f;

    // ---- stage the three 32KB images (async, no VALU) ----
    const size_t cb = (size_t)kh * 16384;
#pragma unroll
    for (int it = 0; it < 8; ++it) {
        int off = (wv * 8 + it) * 512;
        GLD16(khiI + cb + off + lane * 8, &KHI[off]);
        GLD16(kloI + cb + off + lane * 8, &KLO[off]);
        GLD16(cvtI + cb + off + lane * 8, &CVT[off]);
    }

    // ---- Q hi/lo fragments ----
    const int qloc = l31 & 15;
    const int t    = t0 + qloc;
    const int h    = kh * G_ + 2 * wv + (l31 >> 4);
    short8 qhi[8], qlo[8];
    {
        const float* qrow = q + (size_t)t * (H_ * D_) + h * D_;
#pragma unroll
        for (int dc = 0; dc < 8; ++dc) {
            int d0 = dc * 16 + hi * 8;
            float4 x = *reinterpret_cast<const float4*>(qrow + d0);
            float4 y = *reinterpret_cast<const float4*>(qrow + d0 + 4);
            float e_[8] = {x.x, x.y, x.z, x.w, y.x, y.y, y.z, y.w};
            short8 fh, fl;
#pragma unroll
            for (int e = 0; e < 8; ++e) {
                unsigned short hb = f2bf(e_[e]);
                fh[e] = (short)hb;
                fl[e] = (short)f2bf(e_[e] - bf2f(hb));
            }
            qhi[dc] = fh; qlo[dc] = fl;
        }
    }
    __syncthreads();

    // ---- QK^T split-bf16: S^T[j][combo]; dc-outer -> 4 independent chains ----
    f32x16 s_[4];
#pragma unroll
    for (int tl = 0; tl < 4; ++tl)
#pragma unroll
        for (int r = 0; r < 16; ++r) s_[tl][r] = 0.f;
#pragma unroll
    for (int dc = 0; dc < 8; ++dc) {
        int c8 = dc * 2 + hi;
#pragma unroll
        for (int tl = 0; tl < 4; ++tl) {
            int row = tl * 32 + l31;
            int off = row * 128 + ((c8 ^ ((row >> 2) & 7)) << 3);
            short8 ahi = *reinterpret_cast<const short8*>(&KHI[off]);
            short8 alo = *reinterpret_cast<const short8*>(&KLO[off]);
            s_[tl] = __builtin_amdgcn_mfma_f32_32x32x16_bf16(ahi, qhi[dc], s_[tl], 0, 0, 0);
            s_[tl] = __builtin_amdgcn_mfma_f32_32x32x16_bf16(alo, qhi[dc], s_[tl], 0, 0, 0);
            s_[tl] = __builtin_amdgcn_mfma_f32_32x32x16_bf16(ahi, qlo[dc], s_[tl], 0, 0, 0);
        }
    }

    // ---- mask + softmax (per-lane full row; partner holds other 32 j) ----
    const int nv = (t >= 31) ? (((t - 31) >> 4) + 1) : 0;
    float m = -1e30f;
#pragma unroll
    for (int tl = 0; tl < 4; ++tl)
#pragma unroll
        for (int r = 0; r < 16; ++r) {
            int j = tl * 32 + (r & 3) + 8 * (r >> 2) + hi4;
            float lg = (j < nv) ? s_[tl][r] * SCALE : -1e30f;
            s_[tl][r] = lg;
            m = fmaxf(m, lg);
        }
    m = fmaxf(m, __shfl_xor(m, 32));
    float lsum = 0.f;
#pragma unroll
    for (int tl = 0; tl < 4; ++tl)
#pragma unroll
        for (int r = 0; r < 16; ++r) {
            float e = __expf(s_[tl][r] - m);
            s_[tl][r] = e;
            lsum += e;
        }
    lsum += __shfl_xor(lsum, 32);
    const float linv = (nv > 0) ? 1.f / lsum : 0.f;

    // ---- window scores ----
#pragma unroll
    for (int tl = 0; tl < 4; ++tl)
#pragma unroll
        for (int r = 0; r < 16; ++r) {
            int j = tl * 32 + (r & 3) + 8 * (r >> 2) + hi4;
            atomicAdd(&wsc_s[qloc * 132 + j], s_[tl][r] * linv);
        }

    // ---- PV: P->bf16 A-frags, V B-frags = contiguous b128 from CVT image ----
    f32x16 acc[4];
#pragma unroll
    for (int dt = 0; dt < 4; ++dt)
#pragma unroll
        for (int r = 0; r < 16; ++r) acc[dt][r] = 0.f;
#pragma unroll
    for (int kc = 0; kc < 8; ++kc) {
        const int su = kc >> 1, rb = (kc & 1) * 8;
        unsigned pa0, pa1, pb0, pb1;
        asm("v_cvt_pk_bf16_f32 %0, %1, %2" : "=v"(pa0) : "v"(s_[su][rb+0]), "v"(s_[su][rb+1]));
        asm("v_cvt_pk_bf16_f32 %0, %1, %2" : "=v"(pa1) : "v"(s_[su][rb+2]), "v"(s_[su][rb+3]));
        asm("v_cvt_pk_bf16_f32 %0, %1, %2" : "=v"(pb0) : "v"(s_[su][rb+4]), "v"(s_[su][rb+5]));
        asm("v_cvt_pk_bf16_f32 %0, %1, %2" : "=v"(pb1) : "v"(s_[su][rb+6]), "v"(s_[su][rb+7]));
        unsigned sa0 = __shfl_xor(pa0, 32);
        unsigned sa1 = __shfl_xor(pa1, 32);
        unsigned sb0 = __shfl_xor(pb0, 32);
        unsigned sb1 = __shfl_xor(pb1, 32);
        union { unsigned u[4]; short8 s8; } pa;
        pa.u[0] = hi ? sb0 : pa0;
        pa.u[1] = hi ? sb1 : pa1;
        pa.u[2] = hi ? pb0 : sa0;
        pa.u[3] = hi ? pb1 : sa1;
        const int jc8 = kc * 2 + hi;
#pragma unroll
        for (int dt = 0; dt < 4; ++dt) {
            int d = dt * 32 + l31;
            short8 bf = *reinterpret_cast<const short8*>(
                &CVT[d * 128 + ((jc8 ^ ((d >> 2) & 7)) << 3)]);
            acc[dt] = __builtin_amdgcn_mfma_f32_32x32x16_bf16(pa.s8, bf, acc[dt], 0, 0, 0);
        }
    }

    wfac[wv][l31] = w[(size_t)t * (H_ * 3) + h * 3 + 0] * linv;
    __syncthreads();

    float wfr[16];
#pragma unroll
    for (int r = 0; r < 16; ++r)
        wfr[r] = wfac[wv][(r & 3) + 8 * (r >> 2) + hi4];
#pragma unroll
    for (int dt = 0; dt < 4; ++dt)
#pragma unroll
        for (int r = 0; r < 16; ++r) {
            int crow = (r & 3) + 8 * (r >> 2) + hi4;
            int tt = t0 + (crow & 15);
            int hh = kh * G_ + 2 * wv + (crow >> 4);
            out[(size_t)tt * (H_ * D_) + hh * D_ + dt * 32 + l31] = acc[dt][r] * wfr[r];
        }

#pragma unroll
    for (int half = 0; half < 2; ++half) {
        int b  = (tid & 15) + half * 16;
        int qq = tid >> 4;
        int tt = t0 + qq;
        float sc = 0.f;
        int j0 = 4 * b - 1; if (j0 < 0) j0 = 0;
        int j1 = 4 * b + 3; if (j1 > NCMP - 1) j1 = NCMP - 1;
        for (int j = j0; j <= j1; ++j) sc += wsc_s[qq * 132 + j];
        int tb = tt >> 6;
        bool forced = (b == 0) || (b <= tb && b >= tb - 1);
        if (forced) sc = 1e30f;
        if (b * 64 > tt) sc = -1e30f;
        bsc_s[qq * 32 + b] = sc;
    }
    __syncthreads();

#pragma unroll
    for (int half = 0; half < 2; ++half) {
        int b  = (tid & 15) + half * 16;
        int qq = tid >> 4;
        float sb = bsc_s[qq * 32 + b];
        int cnt = 0;
        for (int b2 = 0; b2 < NBLK; ++b2) {
            float s2 = bsc_s[qq * 32 + b2];
            cnt += (s2 > sb) || (s2 == sb && b2 < b);
        }
        if (cnt < TOPN) atomicOr(&sel_s[qq], 1u << b);
    }
    __syncthreads();
    if (tid < 16) sel[kh * T_ + t0 + tid] = sel_s[tid];
}

// ---------- kernel 3: MFMA flash window+selected attention -------------------
// Staging = global_load_lds of prebuilt K/VT images; PV B-frags b128.
__global__ __launch_bounds__(256, 2) void slc_win_mfma(
        const float* __restrict__ q, const unsigned short* __restrict__ kimg,
        const unsigned short* __restrict__ vtimg, const float* __restrict__ w,
        const unsigned int* __restrict__ sel, float* __restrict__ out,
        float* __restrict__ winb, float* __restrict__ slcb, int use_scratch) {
    const int qt    = blockIdx.x;
    const int kh    = blockIdx.y;
    const int phase = blockIdx.z;
    const int t0    = qt * 16;
    const int tid   = threadIdx.x;
    const int wv    = tid >> 6;
    const int lane  = tid & 63;
    const int l31   = lane & 31;
    const int hi    = lane >> 5;
    const int hi4   = hi * 4;

    __shared__ unsigned short Kl[64 * 128];   // K image tile
    __shared__ unsigned short Vt[128 * 64];   // VT image tile
    __shared__ float wfac[4][32];

    const int qloc = l31 & 15;
    const int t    = t0 + qloc;
    const int h    = kh * G_ + 2 * wv + (l31 >> 4);

    short8 qf[8];
    {
        const float* qrow = q + (size_t)t * (H_ * D_) + h * D_;
#pragma unroll
        for (int dc = 0; dc < 8; ++dc) {
            int d0 = dc * 16 + hi * 8;
            float4 x = *reinterpret_cast<const float4*>(qrow + d0);
            float4 y = *reinterpret_cast<const float4*>(qrow + d0 + 4);
            short8 f;
            f[0] = (short)f2bf(x.x); f[1] = (short)f2bf(x.y);
            f[2] = (short)f2bf(x.z); f[3] = (short)f2bf(x.w);
            f[4] = (short)f2bf(y.x); f[5] = (short)f2bf(y.y);
            f[6] = (short)f2bf(y.z); f[7] = (short)f2bf(y.w);
            qf[dc] = f;
        }
    }

    const unsigned int smask = sel[kh * T_ + t];
    const int tbmax = t0 >> 6;
    unsigned int um = 0;
    int b0 = 0;
    if (phase == 0) {
        int lo = t0 - (WIN_ - 1); if (lo < 0) lo = 0;
        b0 = lo >> 6;
    } else {
        unsigned int vm = (tbmax >= 31) ? 0xffffffffu : ((2u << tbmax) - 1u);
        um = smask;
        um |= __shfl_xor(um, 1); um |= __shfl_xor(um, 2);
        um |= __shfl_xor(um, 4); um |= __shfl_xor(um, 8);
        um &= vm;
    }

    f32x16 acc[4];
#pragma unroll
    for (int dt = 0; dt < 4; ++dt)
#pragma unroll
        for (int r = 0; r < 16; ++r) acc[dt][r] = 0.f;
    float m_run = -1e30f, l_run = 0.f;

    int bidx = b0;
    unsigned int rem = um;
    while (true) {
        int b;
        if (phase == 0) { if (bidx > tbmax) break; b = bidx++; }
        else            { if (!rem) break; b = __ffs(rem) - 1; rem &= rem - 1; }
        const int s0 = b << 6;

        __syncthreads();
        // ---- stage K + VT tile images (async 16B copies, zero VALU) ----
        {
            const size_t tb = ((size_t)kh * 32 + b) * 8192;
#pragma unroll
            for (int it = 0; it < 4; ++it) {
                int off = (wv * 4 + it) * 512;
                GLD16(kimg + tb + off + lane * 8, &Kl[off]);
                GLD16(vtimg + tb + off + lane * 8, &Vt[off]);
            }
        }
        __syncthreads();

        // ---- QK^T (swapped): S^T[key][combo] ----
        f32x16 s_[2];
#pragma unroll
        for (int r = 0; r < 16; ++r) { s_[0][r] = 0.f; s_[1][r] = 0.f; }
#pragma unroll
        for (int dc = 0; dc < 8; ++dc) {
            int c8 = dc * 2 + hi;
            int swz = (c8 ^ ((l31 >> 2) & 7)) << 3;
            short8 a0 = *reinterpret_cast<const short8*>(&Kl[l31 * 128 + swz]);
            short8 a1 = *reinterpret_cast<const short8*>(&Kl[(32 + l31) * 128 + swz]);
            s_[0] = __builtin_amdgcn_mfma_f32_32x32x16_bf16(a0, qf[dc], s_[0], 0, 0, 0);
            s_[1] = __builtin_amdgcn_mfma_f32_32x32x16_bf16(a1, qf[dc], s_[1], 0, 0, 0);
        }

        // ---- mask + online softmax (wave-uniform max -> uniform rescale f) ----
        const int sb = (smask >> b) & 1;
        float p_[2][16];
        float mc = -INFINITY;
#pragma unroll
        for (int sub = 0; sub < 2; ++sub)
#pragma unroll
            for (int r = 0; r < 16; ++r) {
                int crow = (r & 3) + 8 * (r >> 2) + hi4;
                int s = s0 + sub * 32 + crow;
                bool ok = (s <= t) && (phase ? (sb != 0) : (s + WIN_ > t));
                float lg = ok ? s_[sub][r] * SCALE : -INFINITY;
                p_[sub][r] = lg;
                mc = fmaxf(mc, lg);
            }
        mc = fmaxf(mc, __shfl_xor(mc, 1));
        mc = fmaxf(mc, __shfl_xor(mc, 2));
        mc = fmaxf(mc, __shfl_xor(mc, 4));
        mc = fmaxf(mc, __shfl_xor(mc, 8));
        mc = fmaxf(mc, __shfl_xor(mc, 16));
        mc = fmaxf(mc, __shfl_xor(mc, 32));
        float mnew = fmaxf(m_run, mc);
        float f = __expf(m_run - mnew);
        float lsum = 0.f;
#pragma unroll
        for (int sub = 0; sub < 2; ++sub)
#pragma unroll
            for (int r = 0; r < 16; ++r) {
                float e = __expf(p_[sub][r] - mnew);
                p_[sub][r] = e;
                lsum += e;
            }
        lsum += __shfl_xor(lsum, 32);
        l_run = l_run * f + lsum;
        m_run = mnew;
#pragma unroll
        for (int dt = 0; dt < 4; ++dt)
#pragma unroll
            for (int r = 0; r < 16; ++r) acc[dt][r] *= f;

        // ---- P -> bf16 A-frags; PV with contiguous b128 VT reads ----
#pragma unroll
        for (int kc = 0; kc < 4; ++kc) {
            const int su = kc >> 1, rb = (kc & 1) * 8;
            unsigned pa0, pb0, pa1, pb1;
            asm("v_cvt_pk_bf16_f32 %0, %1, %2" : "=v"(pa0) : "v"(p_[su][rb+0]), "v"(p_[su][rb+1]));
            asm("v_cvt_pk_bf16_f32 %0, %1, %2" : "=v"(pa1) : "v"(p_[su][rb+2]), "v"(p_[su][rb+3]));
            asm("v_cvt_pk_bf16_f32 %0, %1, %2" : "=v"(pb0) : "v"(p_[su][rb+4]), "v"(p_[su][rb+5]));
            asm("v_cvt_pk_bf16_f32 %0, %1, %2" : "=v"(pb1) : "v"(p_[su][rb+6]), "v"(p_[su][rb+7]));
            unsigned sa0 = __shfl_xor(pa0, 32);
            unsigned sa1 = __shfl_xor(pa1, 32);
            unsigned sb0 = __shfl_xor(pb0, 32);
            unsigned sb1 = __shfl_xor(pb1, 32);
            union { unsigned u[4]; short8 s8; } pa;
            pa.u[0] = hi ? sb0 : pa0;
            pa.u[1] = hi ? sb1 : pa1;
            pa.u[2] = hi ? pb0 : sa0;
            pa.u[3] = hi ? pb1 : sa1;
            const int kc8 = kc * 2 + hi;
#pragma unroll
            for (int dt = 0; dt < 4; ++dt) {
                int d = dt * 32 + l31;
                short8 bf = *reinterpret_cast<const short8*>(
                    &Vt[d * 64 + ((kc8 ^ ((d >> 2) & 7)) << 3)]);
                acc[dt] = __builtin_amdgcn_mfma_f32_32x32x16_bf16(pa.s8, bf, acc[dt], 0, 0, 0);
            }
        }
    }

    float linv = 1.f / l_run;
    int widx = (phase == 0) ? 2 : 1;
    wfac[wv][l31] = w[(size_t)t * (H_ * 3) + h * 3 + widx] * linv;
    __syncthreads();
    float wfr[16];
#pragma unroll
    for (int r = 0; r < 16; ++r)
        wfr[r] = wfac[wv][(r & 3) + 8 * (r >> 2) + hi4];
    float* base = (phase == 0) ? winb : slcb;
#pragma unroll
    for (int dt = 0; dt < 4; ++dt)
#pragma unroll
        for (int r = 0; r < 16; ++r) {
            int crow = (r & 3) + 8 * (r >> 2) + hi4;
            int tt = t0 + (crow & 15);
            int hh = kh * G_ + 2 * wv + (crow >> 4);
            size_t idx = (size_t)tt * (H_ * D_) + hh * D_ + dt * 32 + l31;
            float val = acc[dt][r] * wfr[r];
            if (use_scratch) base[idx] = val;
            else             atomicAdd(&out[idx], val);
        }
}

// ---------- kernel 4: combine (scratch mode only) ----------------------------
__global__ __launch_bounds__(256) void combine_out(float* __restrict__ out,
        const float* __restrict__ a, const float* __restrict__ b) {
    int i = blockIdx.x * 256 + threadIdx.x;
    float4 o = reinterpret_cast<float4*>(out)[i];
    float4 x = reinterpret_cast<const float4*>(a)[i];
    float4 y = reinterpret_cast<const float4*>(b)[i];
    o.x += x.x + y.x; o.y += x.y + y.y; o.z += x.z + y.z; o.w += x.w + y.w;
    reinterpret_cast<float4*>(out)[i] = o;
}

// ---------- launch ----------
extern "C" void kernel_launch(void* const* d_in, const int* in_sizes, int n_in,
                              void* d_out, int out_size, void* d_ws, size_t ws_size,
                              hipStream_t stream) {
    const float* q = (const float*)d_in[0];
    const float* k = (const float*)d_in[1];
    const float* v = (const float*)d_in[2];
    const float* w = (const float*)d_in[3];
    float* out = (float*)d_out;

    char* ws = (char*)d_ws;
    unsigned short* kimg  = (unsigned short*)(ws);                    // 1 MB
    unsigned short* vtimg = (unsigned short*)(ws + (1u << 20));       // 1 MB
    unsigned short* khiI  = (unsigned short*)(ws + (2u << 20));       // 64 KB
    unsigned short* kloI  = (unsigned short*)(ws + (2u << 20) + 65536);
    unsigned short* cvtI  = (unsigned short*)(ws + (2u << 20) + 2 * 65536);
    unsigned short* vflat = (unsigned short*)(ws + (2u << 20) + 3 * 65536);
    unsigned int*   sel   = (unsigned int*)(ws + (2u << 20) + 4 * 65536);  // 16 KB
    float* winb_s = (float*)(ws + (2u << 20) + 4 * 65536 + 16384);
    float* slcb_s = winb_s + (size_t)T_ * H_ * D_;
    const size_t need = (2u << 20) + 4 * 65536 + 16384
                        + 2 * (size_t)T_ * H_ * D_ * sizeof(float);
    const int use_scratch = (ws_size >= need) ? 1 : 0;
    float* winb = use_scratch ? winb_s : out;
    float* slcb = use_scratch ? slcb_s : out;

    hipLaunchKernelGGL(prep_kv, dim3(32, KH_), dim3(256), 0, stream, k, v, kimg, vtimg);
    hipLaunchKernelGGL(build_cmp, dim3(128, KH_), dim3(128), 0, stream,
                       k, v, khiI, kloI, vflat);
    hipLaunchKernelGGL(prep_cmp_img, dim3(KH_), dim3(256), 0, stream, vflat, cvtI);
    hipLaunchKernelGGL(cmp_attn_mfma, dim3(T_ / 16, KH_), dim3(256), 0, stream,
                       q, w, khiI, kloI, cvtI, out, sel);
    hipLaunchKernelGGL(slc_win_mfma, dim3(T_ / 16, KH_, 2), dim3(256), 0, stream,
                       q, kimg, vtimg, w, sel, out, winb, slcb, use_scratch);
    if (use_scratch) {
        hipLaunchKernelGGL(combine_out, dim3((T_ * H_ * D_ / 4) / 256), dim3(256), 0, stream,
                           out, winb, slcb);
    }
}

// Round 7
// 258.662 us; speedup vs baseline: 4.1818x; 1.0134x over previous
//
#include <hip/hip_runtime.h>
#include <hip/hip_bf16.h>
#include <math.h>

#define T_ 2048
#define H_ 16
#define KH_ 2
#define G_ 8
#define D_ 128
#define NCMP 127
#define JP 128
#define NBLK 32
#define TOPN 16
#define WIN_ 512
#define SCALE 0.08838834764831845f

typedef __attribute__((ext_vector_type(8))) short short8;
typedef __attribute__((ext_vector_type(16))) float f32x16;

__device__ __forceinline__ unsigned short f2bf(float x) {
    union { float f; unsigned u; } c; c.f = x;
    unsigned u = c.u + 0x7fffu + ((c.u >> 16) & 1u);
    return (unsigned short)(u >> 16);
}
__device__ __forceinline__ float bf2f(unsigned short b) {
    union { unsigned u; float f; } c; c.u = (unsigned)b << 16; return c.f;
}

// async 16B global->LDS copy (lane i lands at lds + i*16)
#define GLD16(gsrc, lds) \
    __builtin_amdgcn_global_load_lds( \
        (const __attribute__((address_space(1))) unsigned int*)(gsrc), \
        (__attribute__((address_space(3))) unsigned int*)(lds), 16, 0, 0)

// ---------- kernel 0: K/V -> bf16 LDS-image tiles (K row-major, V transposed) --
// Swizzle: granule ^= (row & 7)  [8-lane phase groups read consecutive rows]
//   Kimg [r*128 + ((c ^ (r&7))<<3) + e]   = K[s0+r][c*8+e]      (r<64,c<16)
//   VTimg[d*64  + ((kc8 ^ (d&7))<<3) + e] = V[s0+kc8*8+e][d]    (d<128,kc8<8)
__global__ __launch_bounds__(256) void prep_kv(
        const float* __restrict__ k, const float* __restrict__ v,
        unsigned short* __restrict__ kimg, unsigned short* __restrict__ vtimg) {
    const int b  = blockIdx.x;
    const int kh = blockIdx.y;
    const int s0 = b << 6;
    const int tid = threadIdx.x;
    const size_t tb = ((size_t)kh * 32 + b) * 8192;
#pragma unroll
    for (int it = 0; it < 4; ++it) {
        int idx = it * 256 + tid;
        int r = idx >> 4, c = idx & 15;
        const float* src = k + (size_t)(s0 + r) * (KH_ * D_) + kh * D_ + c * 8;
        float4 x = *reinterpret_cast<const float4*>(src);
        float4 y = *reinterpret_cast<const float4*>(src + 4);
        union { unsigned short u[8]; uint4 q; } o;
        o.u[0] = f2bf(x.x); o.u[1] = f2bf(x.y); o.u[2] = f2bf(x.z); o.u[3] = f2bf(x.w);
        o.u[4] = f2bf(y.x); o.u[5] = f2bf(y.y); o.u[6] = f2bf(y.z); o.u[7] = f2bf(y.w);
        *reinterpret_cast<uint4*>(&kimg[tb + r * 128 + ((c ^ (r & 7)) << 3)]) = o.q;
    }
#pragma unroll
    for (int it = 0; it < 4; ++it) {
        int idx = it * 256 + tid;
        int d = idx & 127, kc8 = idx >> 7;
        union { unsigned short u[8]; uint4 q; } o;
#pragma unroll
        for (int e = 0; e < 8; ++e)
            o.u[e] = f2bf(v[(size_t)(s0 + kc8 * 8 + e) * (KH_ * D_) + kh * D_ + d]);
        *reinterpret_cast<uint4*>(&vtimg[tb + d * 64 + ((kc8 ^ (d & 7)) << 3)]) = o.q;
    }
}

// ---------- kernel 1: compressed means -> khi/klo images + flat v bf16 --------
__global__ __launch_bounds__(128) void build_cmp(
        const float* __restrict__ k, const float* __restrict__ v,
        unsigned short* __restrict__ khiI, unsigned short* __restrict__ kloI,
        unsigned short* __restrict__ vflat) {
    int j  = blockIdx.x;
    int kh = blockIdx.y;
    int d  = threadIdx.x;
    unsigned short hb = 0, lb = 0, vb = 0;
    if (j < NCMP) {
        int s0 = j * 16;
        float sk = 0.f, sv = 0.f;
        for (int i = 0; i < 32; ++i) {
            sk += k[(size_t)(s0 + i) * KH_ * D_ + kh * D_ + d];
            sv += v[(size_t)(s0 + i) * KH_ * D_ + kh * D_ + d];
        }
        float mk = sk * (1.f / 32.f), mv = sv * (1.f / 32.f);
        hb = f2bf(mk);
        lb = f2bf(mk - bf2f(hb));
        vb = f2bf(mv);
    }
    int c = d >> 3;
    size_t ib = (size_t)kh * 16384 + j * 128 + ((c ^ (j & 7)) << 3) + (d & 7);
    khiI[ib] = hb;
    kloI[ib] = lb;
    vflat[(size_t)kh * 16384 + j * 128 + d] = vb;
}

// ---------- kernel 1b: flat cmp-v -> transposed image ------------------------
//   CVTimg[d*128 + ((jc8 ^ (d&7))<<3) + e] = cmpv[jc8*8+e][d]  (jc8<16)
__global__ __launch_bounds__(256) void prep_cmp_img(
        const unsigned short* __restrict__ vflat, unsigned short* __restrict__ cvtI) {
    const int kh = blockIdx.x;
    const int tid = threadIdx.x;
#pragma unroll
    for (int it = 0; it < 8; ++it) {
        int idx = it * 256 + tid;
        int d = idx & 127, jc8 = idx >> 7;
        union { unsigned short u[8]; uint4 q; } o;
#pragma unroll
        for (int e = 0; e < 8; ++e)
            o.u[e] = vflat[(size_t)kh * 16384 + (jc8 * 8 + e) * 128 + d];
        *reinterpret_cast<uint4*>(
            &cvtI[(size_t)kh * 16384 + d * 128 + ((jc8 ^ (d & 7)) << 3)]) = o.q;
    }
}

// ---------- kernel 2: MFMA compressed attention + top-16 selection -----------
__global__ __launch_bounds__(256, 1) void cmp_attn_mfma(
        const float* __restrict__ q, const float* __restrict__ w,
        const unsigned short* __restrict__ khiI, const unsigned short* __restrict__ kloI,
        const unsigned short* __restrict__ cvtI,
        float* __restrict__ out, unsigned int* __restrict__ sel) {
    const int qt  = blockIdx.x;
    const int kh  = blockIdx.y;
    const int t0  = qt * 16;
    const int tid = threadIdx.x;
    const int wv  = tid >> 6;
    const int lane = tid & 63;
    const int l31 = lane & 31;
    const int hi  = lane >> 5;
    const int hi4 = hi * 4;

    __shared__ unsigned short KHI[JP * D_];
    __shared__ unsigned short KLO[JP * D_];
    __shared__ unsigned short CVT[JP * D_];
    __shared__ float wsc_s[16 * 132];
    __shared__ float bsc_s[16 * 32];
    __shared__ unsigned int sel_s[16];
    __shared__ float wfac[4][32];

    if (tid < 16) sel_s[tid] = 0u;
    for (int i = tid; i < 16 * 132; i += 256) wsc_s[i] = 0.f;

    const size_t cb = (size_t)kh * 16384;
#pragma unroll
    for (int it = 0; it < 8; ++it) {
        int off = (wv * 8 + it) * 512;
        GLD16(khiI + cb + off + lane * 8, &KHI[off]);
        GLD16(kloI + cb + off + lane * 8, &KLO[off]);
        GLD16(cvtI + cb + off + lane * 8, &CVT[off]);
    }

    const int qloc = l31 & 15;
    const int t    = t0 + qloc;
    const int h    = kh * G_ + 2 * wv + (l31 >> 4);
    short8 qhi[8], qlo[8];
    {
        const float* qrow = q + (size_t)t * (H_ * D_) + h * D_;
#pragma unroll
        for (int dc = 0; dc < 8; ++dc) {
            int d0 = dc * 16 + hi * 8;
            float4 x = *reinterpret_cast<const float4*>(qrow + d0);
            float4 y = *reinterpret_cast<const float4*>(qrow + d0 + 4);
            float e_[8] = {x.x, x.y, x.z, x.w, y.x, y.y, y.z, y.w};
            short8 fh, fl;
#pragma unroll
            for (int e = 0; e < 8; ++e) {
                unsigned short hb = f2bf(e_[e]);
                fh[e] = (short)hb;
                fl[e] = (short)f2bf(e_[e] - bf2f(hb));
            }
            qhi[dc] = fh; qlo[dc] = fl;
        }
    }
    __syncthreads();

    // QK^T split-bf16: S^T[j][combo]
    f32x16 s_[4];
#pragma unroll
    for (int tl = 0; tl < 4; ++tl)
#pragma unroll
        for (int r = 0; r < 16; ++r) s_[tl][r] = 0.f;
    __builtin_amdgcn_s_setprio(1);
#pragma unroll
    for (int dc = 0; dc < 8; ++dc) {
        int c8 = dc * 2 + hi;
        int swz = (c8 ^ (l31 & 7)) << 3;
#pragma unroll
        for (int tl = 0; tl < 4; ++tl) {
            int off = (tl * 32 + l31) * 128 + swz;
            short8 ahi = *reinterpret_cast<const short8*>(&KHI[off]);
            short8 alo = *reinterpret_cast<const short8*>(&KLO[off]);
            s_[tl] = __builtin_amdgcn_mfma_f32_32x32x16_bf16(ahi, qhi[dc], s_[tl], 0, 0, 0);
            s_[tl] = __builtin_amdgcn_mfma_f32_32x32x16_bf16(alo, qhi[dc], s_[tl], 0, 0, 0);
            s_[tl] = __builtin_amdgcn_mfma_f32_32x32x16_bf16(ahi, qlo[dc], s_[tl], 0, 0, 0);
        }
    }
    __builtin_amdgcn_s_setprio(0);

    const int nv = (t >= 31) ? (((t - 31) >> 4) + 1) : 0;
    float m = -1e30f;
#pragma unroll
    for (int tl = 0; tl < 4; ++tl)
#pragma unroll
        for (int r = 0; r < 16; ++r) {
            int j = tl * 32 + (r & 3) + 8 * (r >> 2) + hi4;
            float lg = (j < nv) ? s_[tl][r] * SCALE : -1e30f;
            s_[tl][r] = lg;
            m = fmaxf(m, lg);
        }
    m = fmaxf(m, __shfl_xor(m, 32));
    float lsum = 0.f;
#pragma unroll
    for (int tl = 0; tl < 4; ++tl)
#pragma unroll
        for (int r = 0; r < 16; ++r) {
            float e = __expf(s_[tl][r] - m);
            s_[tl][r] = e;
            lsum += e;
        }
    lsum += __shfl_xor(lsum, 32);
    const float linv = (nv > 0) ? 1.f / lsum : 0.f;

#pragma unroll
    for (int tl = 0; tl < 4; ++tl)
#pragma unroll
        for (int r = 0; r < 16; ++r) {
            int j = tl * 32 + (r & 3) + 8 * (r >> 2) + hi4;
            atomicAdd(&wsc_s[qloc * 132 + j], s_[tl][r] * linv);
        }

    // PV
    f32x16 acc[4];
#pragma unroll
    for (int dt = 0; dt < 4; ++dt)
#pragma unroll
        for (int r = 0; r < 16; ++r) acc[dt][r] = 0.f;
#pragma unroll
    for (int kc = 0; kc < 8; ++kc) {
        const int su = kc >> 1, rb = (kc & 1) * 8;
        unsigned pa0, pa1, pb0, pb1;
        asm("v_cvt_pk_bf16_f32 %0, %1, %2" : "=v"(pa0) : "v"(s_[su][rb+0]), "v"(s_[su][rb+1]));
        asm("v_cvt_pk_bf16_f32 %0, %1, %2" : "=v"(pa1) : "v"(s_[su][rb+2]), "v"(s_[su][rb+3]));
        asm("v_cvt_pk_bf16_f32 %0, %1, %2" : "=v"(pb0) : "v"(s_[su][rb+4]), "v"(s_[su][rb+5]));
        asm("v_cvt_pk_bf16_f32 %0, %1, %2" : "=v"(pb1) : "v"(s_[su][rb+6]), "v"(s_[su][rb+7]));
        unsigned sa0 = __shfl_xor(pa0, 32);
        unsigned sa1 = __shfl_xor(pa1, 32);
        unsigned sb0 = __shfl_xor(pb0, 32);
        unsigned sb1 = __shfl_xor(pb1, 32);
        union { unsigned u[4]; short8 s8; } pa;
        pa.u[0] = hi ? sb0 : pa0;
        pa.u[1] = hi ? sb1 : pa1;
        pa.u[2] = hi ? pb0 : sa0;
        pa.u[3] = hi ? pb1 : sa1;
        const int jc8 = kc * 2 + hi;
        __builtin_amdgcn_s_setprio(1);
#pragma unroll
        for (int dt = 0; dt < 4; ++dt) {
            int d = dt * 32 + l31;
            short8 bf = *reinterpret_cast<const short8*>(
                &CVT[d * 128 + ((jc8 ^ (d & 7)) << 3)]);
            acc[dt] = __builtin_amdgcn_mfma_f32_32x32x16_bf16(pa.s8, bf, acc[dt], 0, 0, 0);
        }
        __builtin_amdgcn_s_setprio(0);
    }

    wfac[wv][l31] = w[(size_t)t * (H_ * 3) + h * 3 + 0] * linv;
    __syncthreads();

    float wfr[16];
#pragma unroll
    for (int r = 0; r < 16; ++r)
        wfr[r] = wfac[wv][(r & 3) + 8 * (r >> 2) + hi4];
#pragma unroll
    for (int dt = 0; dt < 4; ++dt)
#pragma unroll
        for (int r = 0; r < 16; ++r) {
            int crow = (r & 3) + 8 * (r >> 2) + hi4;
            int tt = t0 + (crow & 15);
            int hh = kh * G_ + 2 * wv + (crow >> 4);
            out[(size_t)tt * (H_ * D_) + hh * D_ + dt * 32 + l31] = acc[dt][r] * wfr[r];
        }

#pragma unroll
    for (int half = 0; half < 2; ++half) {
        int b  = (tid & 15) + half * 16;
        int qq = tid >> 4;
        int tt = t0 + qq;
        float sc = 0.f;
        int j0 = 4 * b - 1; if (j0 < 0) j0 = 0;
        int j1 = 4 * b + 3; if (j1 > NCMP - 1) j1 = NCMP - 1;
        for (int j = j0; j <= j1; ++j) sc += wsc_s[qq * 132 + j];
        int tb = tt >> 6;
        bool forced = (b == 0) || (b <= tb && b >= tb - 1);
        if (forced) sc = 1e30f;
        if (b * 64 > tt) sc = -1e30f;
        bsc_s[qq * 32 + b] = sc;
    }
    __syncthreads();

#pragma unroll
    for (int half = 0; half < 2; ++half) {
        int b  = (tid & 15) + half * 16;
        int qq = tid >> 4;
        float sb = bsc_s[qq * 32 + b];
        int cnt = 0;
        for (int b2 = 0; b2 < NBLK; ++b2) {
            float s2 = bsc_s[qq * 32 + b2];
            cnt += (s2 > sb) || (s2 == sb && b2 < b);
        }
        if (cnt < TOPN) atomicOr(&sel_s[qq], 1u << b);
    }
    __syncthreads();
    if (tid < 16) sel[kh * T_ + t0 + tid] = sel_s[tid];
}

// ---------- kernel 3: MFMA flash window+selected attention -------------------
// Double-buffered staging (T3 2-phase: issue next STAGE before compute, one
// barrier per tile). phase1 blocks take reversed qt for CU load balance.
__global__ __launch_bounds__(256, 2) void slc_win_mfma(
        const float* __restrict__ q, const unsigned short* __restrict__ kimg,
        const unsigned short* __restrict__ vtimg, const float* __restrict__ w,
        const unsigned int* __restrict__ sel, float* __restrict__ out,
        float* __restrict__ winb, float* __restrict__ slcb, int use_scratch) {
    const int phase = blockIdx.z;
    const int qt    = phase ? (gridDim.x - 1 - blockIdx.x) : blockIdx.x;
    const int kh    = blockIdx.y;
    const int t0    = qt * 16;
    const int tid   = threadIdx.x;
    const int wv    = tid >> 6;
    const int lane  = tid & 63;
    const int l31   = lane & 31;
    const int hi    = lane >> 5;
    const int hi4   = hi * 4;

    __shared__ unsigned short Kl[2][64 * 128];
    __shared__ unsigned short Vt[2][128 * 64];
    __shared__ float wfac[4][32];

    const int qloc = l31 & 15;
    const int t    = t0 + qloc;
    const int h    = kh * G_ + 2 * wv + (l31 >> 4);

    short8 qf[8];
    {
        const float* qrow = q + (size_t)t * (H_ * D_) + h * D_;
#pragma unroll
        for (int dc = 0; dc < 8; ++dc) {
            int d0 = dc * 16 + hi * 8;
            float4 x = *reinterpret_cast<const float4*>(qrow + d0);
            float4 y = *reinterpret_cast<const float4*>(qrow + d0 + 4);
            short8 f;
            f[0] = (short)f2bf(x.x); f[1] = (short)f2bf(x.y);
            f[2] = (short)f2bf(x.z); f[3] = (short)f2bf(x.w);
            f[4] = (short)f2bf(y.x); f[5] = (short)f2bf(y.y);
            f[6] = (short)f2bf(y.z); f[7] = (short)f2bf(y.w);
            qf[dc] = f;
        }
    }

    const unsigned int smask = sel[kh * T_ + t];
    const int tbmax = t0 >> 6;
    unsigned int rem = 0;
    int bidx = 0;
    if (phase == 0) {
        int lo = t0 - (WIN_ - 1); if (lo < 0) lo = 0;
        bidx = lo >> 6;
    } else {
        unsigned int vm = (tbmax >= 31) ? 0xffffffffu : ((2u << tbmax) - 1u);
        rem = smask;
        rem |= __shfl_xor(rem, 1); rem |= __shfl_xor(rem, 2);
        rem |= __shfl_xor(rem, 4); rem |= __shfl_xor(rem, 8);
        rem &= vm;
    }

    f32x16 acc[4];
#pragma unroll
    for (int dt = 0; dt < 4; ++dt)
#pragma unroll
        for (int r = 0; r < 16; ++r) acc[dt][r] = 0.f;
    float m_run = -1e30f, l_run = 0.f;

    // --- pull first tile index ---
    int b_cur;
    if (phase == 0) b_cur = bidx++;
    else { b_cur = rem ? (__ffs(rem) - 1) : -1; if (rem) rem &= rem - 1; }

    // --- stage first tile ---
    if (b_cur >= 0) {
        const size_t tb = ((size_t)kh * 32 + b_cur) * 8192;
#pragma unroll
        for (int it = 0; it < 4; ++it) {
            int off = (wv * 4 + it) * 512;
            GLD16(kimg + tb + off + lane * 8, &Kl[0][off]);
            GLD16(vtimg + tb + off + lane * 8, &Vt[0][off]);
        }
    }
    __syncthreads();

    int cur = 0;
    while (b_cur >= 0) {
        // next tile index
        int b_next;
        if (phase == 0) b_next = (bidx <= tbmax) ? bidx++ : -1;
        else { b_next = rem ? (__ffs(rem) - 1) : -1; if (rem) rem &= rem - 1; }

        // prefetch next tile into other buffer
        if (b_next >= 0) {
            const size_t tb = ((size_t)kh * 32 + b_next) * 8192;
#pragma unroll
            for (int it = 0; it < 4; ++it) {
                int off = (wv * 4 + it) * 512;
                GLD16(kimg + tb + off + lane * 8, &Kl[cur ^ 1][off]);
                GLD16(vtimg + tb + off + lane * 8, &Vt[cur ^ 1][off]);
            }
        }

        const unsigned short* Kc = Kl[cur];
        const unsigned short* Vc = Vt[cur];
        const int s0 = b_cur << 6;

        // ---- QK^T (swapped): S^T[key][combo] ----
        f32x16 s_[2];
#pragma unroll
        for (int r = 0; r < 16; ++r) { s_[0][r] = 0.f; s_[1][r] = 0.f; }
        __builtin_amdgcn_s_setprio(1);
#pragma unroll
        for (int dc = 0; dc < 8; ++dc) {
            int c8 = dc * 2 + hi;
            int swz = (c8 ^ (l31 & 7)) << 3;
            short8 a0 = *reinterpret_cast<const short8*>(&Kc[l31 * 128 + swz]);
            short8 a1 = *reinterpret_cast<const short8*>(&Kc[(32 + l31) * 128 + swz]);
            s_[0] = __builtin_amdgcn_mfma_f32_32x32x16_bf16(a0, qf[dc], s_[0], 0, 0, 0);
            s_[1] = __builtin_amdgcn_mfma_f32_32x32x16_bf16(a1, qf[dc], s_[1], 0, 0, 0);
        }
        __builtin_amdgcn_s_setprio(0);

        // ---- mask + online softmax (wave-uniform max -> uniform rescale f) ----
        const int sb = (smask >> b_cur) & 1;
        float p_[2][16];
        float mc = -INFINITY;
#pragma unroll
        for (int sub = 0; sub < 2; ++sub)
#pragma unroll
            for (int r = 0; r < 16; ++r) {
                int crow = (r & 3) + 8 * (r >> 2) + hi4;
                int s = s0 + sub * 32 + crow;
                bool ok = (s <= t) && (phase ? (sb != 0) : (s + WIN_ > t));
                float lg = ok ? s_[sub][r] * SCALE : -INFINITY;
                p_[sub][r] = lg;
                mc = fmaxf(mc, lg);
            }
        mc = fmaxf(mc, __shfl_xor(mc, 1));
        mc = fmaxf(mc, __shfl_xor(mc, 2));
        mc = fmaxf(mc, __shfl_xor(mc, 4));
        mc = fmaxf(mc, __shfl_xor(mc, 8));
        mc = fmaxf(mc, __shfl_xor(mc, 16));
        mc = fmaxf(mc, __shfl_xor(mc, 32));
        float mnew = fmaxf(m_run, mc);
        float f = __expf(m_run - mnew);
        float lsum = 0.f;
#pragma unroll
        for (int sub = 0; sub < 2; ++sub)
#pragma unroll
            for (int r = 0; r < 16; ++r) {
                float e = __expf(p_[sub][r] - mnew);
                p_[sub][r] = e;
                lsum += e;
            }
        lsum += __shfl_xor(lsum, 32);
        l_run = l_run * f + lsum;
        m_run = mnew;
#pragma unroll
        for (int dt = 0; dt < 4; ++dt)
#pragma unroll
            for (int r = 0; r < 16; ++r) acc[dt][r] *= f;

        // ---- P -> bf16 A-frags; PV with contiguous b128 VT reads ----
#pragma unroll
        for (int kc = 0; kc < 4; ++kc) {
            const int su = kc >> 1, rb = (kc & 1) * 8;
            unsigned pa0, pb0, pa1, pb1;
            asm("v_cvt_pk_bf16_f32 %0, %1, %2" : "=v"(pa0) : "v"(p_[su][rb+0]), "v"(p_[su][rb+1]));
            asm("v_cvt_pk_bf16_f32 %0, %1, %2" : "=v"(pa1) : "v"(p_[su][rb+2]), "v"(p_[su][rb+3]));
            asm("v_cvt_pk_bf16_f32 %0, %1, %2" : "=v"(pb0) : "v"(p_[su][rb+4]), "v"(p_[su][rb+5]));
            asm("v_cvt_pk_bf16_f32 %0, %1, %2" : "=v"(pb1) : "v"(p_[su][rb+6]), "v"(p_[su][rb+7]));
            unsigned sa0 = __shfl_xor(pa0, 32);
            unsigned sa1 = __shfl_xor(pa1, 32);
            unsigned sb0 = __shfl_xor(pb0, 32);
            unsigned sb1 = __shfl_xor(pb1, 32);
            union { unsigned u[4]; short8 s8; } pa;
            pa.u[0] = hi ? sb0 : pa0;
            pa.u[1] = hi ? sb1 : pa1;
            pa.u[2] = hi ? pb0 : sa0;
            pa.u[3] = hi ? pb1 : sa1;
            const int kc8 = kc * 2 + hi;
            __builtin_amdgcn_s_setprio(1);
#pragma unroll
            for (int dt = 0; dt < 4; ++dt) {
                int d = dt * 32 + l31;
                short8 bf = *reinterpret_cast<const short8*>(
                    &Vc[d * 64 + ((kc8 ^ (d & 7)) << 3)]);
                acc[dt] = __builtin_amdgcn_mfma_f32_32x32x16_bf16(pa.s8, bf, acc[dt], 0, 0, 0);
            }
            __builtin_amdgcn_s_setprio(0);
        }

        __syncthreads();   // drains prefetch (vmcnt) + LDS reads (lgkm)
        b_cur = b_next;
        cur ^= 1;
    }

    float linv = 1.f / l_run;
    int widx = (phase == 0) ? 2 : 1;
    wfac[wv][l31] = w[(size_t)t * (H_ * 3) + h * 3 + widx] * linv;
    __syncthreads();
    float wfr[16];
#pragma unroll
    for (int r = 0; r < 16; ++r)
        wfr[r] = wfac[wv][(r & 3) + 8 * (r >> 2) + hi4];
    float* base = (phase == 0) ? winb : slcb;
#pragma unroll
    for (int dt = 0; dt < 4; ++dt)
#pragma unroll
        for (int r = 0; r < 16; ++r) {
            int crow = (r & 3) + 8 * (r >> 2) + hi4;
            int tt = t0 + (crow & 15);
            int hh = kh * G_ + 2 * wv + (crow >> 4);
            size_t idx = (size_t)tt * (H_ * D_) + hh * D_ + dt * 32 + l31;
            float val = acc[dt][r] * wfr[r];
            if (use_scratch) base[idx] = val;
            else             atomicAdd(&out[idx], val);
        }
}

// ---------- kernel 4: combine (scratch mode only) ----------------------------
__global__ __launch_bounds__(256) void combine_out(float* __restrict__ out,
        const float* __restrict__ a, const float* __restrict__ b) {
    int i = blockIdx.x * 256 + threadIdx.x;
    float4 o = reinterpret_cast<float4*>(out)[i];
    float4 x = reinterpret_cast<const float4*>(a)[i];
    float4 y = reinterpret_cast<const float4*>(b)[i];
    o.x += x.x + y.x; o.y += x.y + y.y; o.z += x.z + y.z; o.w += x.w + y.w;
    reinterpret_cast<float4*>(out)[i] = o;
}

// ---------- launch ----------
extern "C" void kernel_launch(void* const* d_in, const int* in_sizes, int n_in,
                              void* d_out, int out_size, void* d_ws, size_t ws_size,
                              hipStream_t stream) {
    const float* q = (const float*)d_in[0];
    const float* k = (const float*)d_in[1];
    const float* v = (const float*)d_in[2];
    const float* w = (const float*)d_in[3];
    float* out = (float*)d_out;

    char* ws = (char*)d_ws;
    unsigned short* kimg  = (unsigned short*)(ws);                    // 1 MB
    unsigned short* vtimg = (unsigned short*)(ws + (1u << 20));       // 1 MB
    unsigned short* khiI  = (unsigned short*)(ws + (2u << 20));       // 64 KB
    unsigned short* kloI  = (unsigned short*)(ws + (2u << 20) + 65536);
    unsigned short* cvtI  = (unsigned short*)(ws + (2u << 20) + 2 * 65536);
    unsigned short* vflat = (unsigned short*)(ws + (2u << 20) + 3 * 65536);
    unsigned int*   sel   = (unsigned int*)(ws + (2u << 20) + 4 * 65536);  // 16 KB
    float* winb_s = (float*)(ws + (2u << 20) + 4 * 65536 + 16384);
    float* slcb_s = winb_s + (size_t)T_ * H_ * D_;
    const size_t need = (2u << 20) + 4 * 65536 + 16384
                        + 2 * (size_t)T_ * H_ * D_ * sizeof(float);
    const int use_scratch = (ws_size >= need) ? 1 : 0;
    float* winb = use_scratch ? winb_s : out;
    float* slcb = use_scratch ? slcb_s : out;

    hipLaunchKernelGGL(prep_kv, dim3(32, KH_), dim3(256), 0, stream, k, v, kimg, vtimg);
    hipLaunchKernelGGL(build_cmp, dim3(128, KH_), dim3(128), 0, stream,
                       k, v, khiI, kloI, vflat);
    hipLaunchKernelGGL(prep_cmp_img, dim3(KH_), dim3(256), 0, stream, vflat, cvtI);
    hipLaunchKernelGGL(cmp_attn_mfma, dim3(T_ / 16, KH_), dim3(256), 0, stream,
                       q, w, khiI, kloI, cvtI, out, sel);
    hipLaunchKernelGGL(slc_win_mfma, dim3(T_ / 16, KH_, 2), dim3(256), 0, stream,
                       q, kimg, vtimg, w, sel, out, winb, slcb, use_scratch);
    if (use_scratch) {
        hipLaunchKernelGGL(combine_out, dim3((T_ * H_ * D_ / 4) / 256), dim3(256), 0, stream,
                           out, winb, slcb);
    }
}

// Round 8
// 226.354 us; speedup vs baseline: 4.7787x; 1.1427x over previous
//
#include <hip/hip_runtime.h>
#include <hip/hip_bf16.h>
#include <math.h>

#define T_ 2048
#define H_ 16
#define KH_ 2
#define G_ 8
#define D_ 128
#define NCMP 127
#define JP 128
#define NBLK 32
#define TOPN 16
#define WIN_ 512
#define SCALE 0.08838834764831845f
#define SCL2 (0.08838834764831845f * 1.4426950408889634f)   // SCALE * log2(e)
#define THR2 11.541560f                                      // 8 * log2(e)

typedef __attribute__((ext_vector_type(8))) short short8;
typedef __attribute__((ext_vector_type(16))) float f32x16;

__device__ __forceinline__ unsigned short f2bf(float x) {
    union { float f; unsigned u; } c; c.f = x;
    unsigned u = c.u + 0x7fffu + ((c.u >> 16) & 1u);
    return (unsigned short)(u >> 16);
}
__device__ __forceinline__ float bf2f(unsigned short b) {
    union { unsigned u; float f; } c; c.u = (unsigned)b << 16; return c.f;
}
__device__ __forceinline__ float exp2_fast(float x) {
    float r;
    asm("v_exp_f32 %0, %1" : "=v"(r) : "v"(x));
    return r;
}

// async 16B global->LDS copy (lane i lands at lds + i*16)
#define GLD16(gsrc, lds) \
    __builtin_amdgcn_global_load_lds( \
        (const __attribute__((address_space(1))) unsigned int*)(gsrc), \
        (__attribute__((address_space(3))) unsigned int*)(lds), 16, 0, 0)

// ---------- kernel 0: K/V -> bf16 LDS-image tiles (unchanged from round 7) ----
__global__ __launch_bounds__(256) void prep_kv(
        const float* __restrict__ k, const float* __restrict__ v,
        unsigned short* __restrict__ kimg, unsigned short* __restrict__ vtimg) {
    const int b  = blockIdx.x;
    const int kh = blockIdx.y;
    const int s0 = b << 6;
    const int tid = threadIdx.x;
    const size_t tb = ((size_t)kh * 32 + b) * 8192;
#pragma unroll
    for (int it = 0; it < 4; ++it) {
        int idx = it * 256 + tid;
        int r = idx >> 4, c = idx & 15;
        const float* src = k + (size_t)(s0 + r) * (KH_ * D_) + kh * D_ + c * 8;
        float4 x = *reinterpret_cast<const float4*>(src);
        float4 y = *reinterpret_cast<const float4*>(src + 4);
        union { unsigned short u[8]; uint4 q; } o;
        o.u[0] = f2bf(x.x); o.u[1] = f2bf(x.y); o.u[2] = f2bf(x.z); o.u[3] = f2bf(x.w);
        o.u[4] = f2bf(y.x); o.u[5] = f2bf(y.y); o.u[6] = f2bf(y.z); o.u[7] = f2bf(y.w);
        *reinterpret_cast<uint4*>(&kimg[tb + r * 128 + ((c ^ (r & 7)) << 3)]) = o.q;
    }
#pragma unroll
    for (int it = 0; it < 4; ++it) {
        int idx = it * 256 + tid;
        int d = idx & 127, kc8 = idx >> 7;
        union { unsigned short u[8]; uint4 q; } o;
#pragma unroll
        for (int e = 0; e < 8; ++e)
            o.u[e] = f2bf(v[(size_t)(s0 + kc8 * 8 + e) * (KH_ * D_) + kh * D_ + d]);
        *reinterpret_cast<uint4*>(&vtimg[tb + d * 64 + ((kc8 ^ (d & 7)) << 3)]) = o.q;
    }
}

// ---------- kernel 1: compressed means -> khi/klo images (unchanged) ----------
__global__ __launch_bounds__(128) void build_cmp(
        const float* __restrict__ k, const float* __restrict__ v,
        unsigned short* __restrict__ khiI, unsigned short* __restrict__ kloI,
        unsigned short* __restrict__ vflat) {
    int j  = blockIdx.x;
    int kh = blockIdx.y;
    int d  = threadIdx.x;
    unsigned short hb = 0, lb = 0, vb = 0;
    if (j < NCMP) {
        int s0 = j * 16;
        float sk = 0.f, sv = 0.f;
        for (int i = 0; i < 32; ++i) {
            sk += k[(size_t)(s0 + i) * KH_ * D_ + kh * D_ + d];
            sv += v[(size_t)(s0 + i) * KH_ * D_ + kh * D_ + d];
        }
        float mk = sk * (1.f / 32.f), mv = sv * (1.f / 32.f);
        hb = f2bf(mk);
        lb = f2bf(mk - bf2f(hb));
        vb = f2bf(mv);
    }
    int c = d >> 3;
    size_t ib = (size_t)kh * 16384 + j * 128 + ((c ^ (j & 7)) << 3) + (d & 7);
    khiI[ib] = hb;
    kloI[ib] = lb;
    vflat[(size_t)kh * 16384 + j * 128 + d] = vb;
}

// ---------- kernel 1b: flat cmp-v -> transposed image (unchanged) -------------
__global__ __launch_bounds__(256) void prep_cmp_img(
        const unsigned short* __restrict__ vflat, unsigned short* __restrict__ cvtI) {
    const int kh = blockIdx.x;
    const int tid = threadIdx.x;
#pragma unroll
    for (int it = 0; it < 8; ++it) {
        int idx = it * 256 + tid;
        int d = idx & 127, jc8 = idx >> 7;
        union { unsigned short u[8]; uint4 q; } o;
#pragma unroll
        for (int e = 0; e < 8; ++e)
            o.u[e] = vflat[(size_t)kh * 16384 + (jc8 * 8 + e) * 128 + d];
        *reinterpret_cast<uint4*>(
            &cvtI[(size_t)kh * 16384 + d * 128 + ((jc8 ^ (d & 7)) << 3)]) = o.q;
    }
}

// ---------- kernel 2: MFMA compressed attention + top-16 (unchanged) ----------
__global__ __launch_bounds__(256, 1) void cmp_attn_mfma(
        const float* __restrict__ q, const float* __restrict__ w,
        const unsigned short* __restrict__ khiI, const unsigned short* __restrict__ kloI,
        const unsigned short* __restrict__ cvtI,
        float* __restrict__ out, unsigned int* __restrict__ sel) {
    const int qt  = blockIdx.x;
    const int kh  = blockIdx.y;
    const int t0  = qt * 16;
    const int tid = threadIdx.x;
    const int wv  = tid >> 6;
    const int lane = tid & 63;
    const int l31 = lane & 31;
    const int hi  = lane >> 5;
    const int hi4 = hi * 4;

    __shared__ unsigned short KHI[JP * D_];
    __shared__ unsigned short KLO[JP * D_];
    __shared__ unsigned short CVT[JP * D_];
    __shared__ float wsc_s[16 * 132];
    __shared__ float bsc_s[16 * 32];
    __shared__ unsigned int sel_s[16];
    __shared__ float wfac[4][32];

    if (tid < 16) sel_s[tid] = 0u;
    for (int i = tid; i < 16 * 132; i += 256) wsc_s[i] = 0.f;

    const size_t cb = (size_t)kh * 16384;
#pragma unroll
    for (int it = 0; it < 8; ++it) {
        int off = (wv * 8 + it) * 512;
        GLD16(khiI + cb + off + lane * 8, &KHI[off]);
        GLD16(kloI + cb + off + lane * 8, &KLO[off]);
        GLD16(cvtI + cb + off + lane * 8, &CVT[off]);
    }

    const int qloc = l31 & 15;
    const int t    = t0 + qloc;
    const int h    = kh * G_ + 2 * wv + (l31 >> 4);
    short8 qhi[8], qlo[8];
    {
        const float* qrow = q + (size_t)t * (H_ * D_) + h * D_;
#pragma unroll
        for (int dc = 0; dc < 8; ++dc) {
            int d0 = dc * 16 + hi * 8;
            float4 x = *reinterpret_cast<const float4*>(qrow + d0);
            float4 y = *reinterpret_cast<const float4*>(qrow + d0 + 4);
            float e_[8] = {x.x, x.y, x.z, x.w, y.x, y.y, y.z, y.w};
            short8 fh, fl;
#pragma unroll
            for (int e = 0; e < 8; ++e) {
                unsigned short hb = f2bf(e_[e]);
                fh[e] = (short)hb;
                fl[e] = (short)f2bf(e_[e] - bf2f(hb));
            }
            qhi[dc] = fh; qlo[dc] = fl;
        }
    }
    __syncthreads();

    f32x16 s_[4];
#pragma unroll
    for (int tl = 0; tl < 4; ++tl)
#pragma unroll
        for (int r = 0; r < 16; ++r) s_[tl][r] = 0.f;
    __builtin_amdgcn_s_setprio(1);
#pragma unroll
    for (int dc = 0; dc < 8; ++dc) {
        int c8 = dc * 2 + hi;
        int swz = (c8 ^ (l31 & 7)) << 3;
#pragma unroll
        for (int tl = 0; tl < 4; ++tl) {
            int off = (tl * 32 + l31) * 128 + swz;
            short8 ahi = *reinterpret_cast<const short8*>(&KHI[off]);
            short8 alo = *reinterpret_cast<const short8*>(&KLO[off]);
            s_[tl] = __builtin_amdgcn_mfma_f32_32x32x16_bf16(ahi, qhi[dc], s_[tl], 0, 0, 0);
            s_[tl] = __builtin_amdgcn_mfma_f32_32x32x16_bf16(alo, qhi[dc], s_[tl], 0, 0, 0);
            s_[tl] = __builtin_amdgcn_mfma_f32_32x32x16_bf16(ahi, qlo[dc], s_[tl], 0, 0, 0);
        }
    }
    __builtin_amdgcn_s_setprio(0);

    const int nv = (t >= 31) ? (((t - 31) >> 4) + 1) : 0;
    float m = -1e30f;
#pragma unroll
    for (int tl = 0; tl < 4; ++tl)
#pragma unroll
        for (int r = 0; r < 16; ++r) {
            int j = tl * 32 + (r & 3) + 8 * (r >> 2) + hi4;
            float lg = (j < nv) ? s_[tl][r] * SCALE : -1e30f;
            s_[tl][r] = lg;
            m = fmaxf(m, lg);
        }
    m = fmaxf(m, __shfl_xor(m, 32));
    float lsum = 0.f;
#pragma unroll
    for (int tl = 0; tl < 4; ++tl)
#pragma unroll
        for (int r = 0; r < 16; ++r) {
            float e = __expf(s_[tl][r] - m);
            s_[tl][r] = e;
            lsum += e;
        }
    lsum += __shfl_xor(lsum, 32);
    const float linv = (nv > 0) ? 1.f / lsum : 0.f;

#pragma unroll
    for (int tl = 0; tl < 4; ++tl)
#pragma unroll
        for (int r = 0; r < 16; ++r) {
            int j = tl * 32 + (r & 3) + 8 * (r >> 2) + hi4;
            atomicAdd(&wsc_s[qloc * 132 + j], s_[tl][r] * linv);
        }

    f32x16 acc[4];
#pragma unroll
    for (int dt = 0; dt < 4; ++dt)
#pragma unroll
        for (int r = 0; r < 16; ++r) acc[dt][r] = 0.f;
#pragma unroll
    for (int kc = 0; kc < 8; ++kc) {
        const int su = kc >> 1, rb = (kc & 1) * 8;
        unsigned pa0, pa1, pb0, pb1;
        asm("v_cvt_pk_bf16_f32 %0, %1, %2" : "=v"(pa0) : "v"(s_[su][rb+0]), "v"(s_[su][rb+1]));
        asm("v_cvt_pk_bf16_f32 %0, %1, %2" : "=v"(pa1) : "v"(s_[su][rb+2]), "v"(s_[su][rb+3]));
        asm("v_cvt_pk_bf16_f32 %0, %1, %2" : "=v"(pb0) : "v"(s_[su][rb+4]), "v"(s_[su][rb+5]));
        asm("v_cvt_pk_bf16_f32 %0, %1, %2" : "=v"(pb1) : "v"(s_[su][rb+6]), "v"(s_[su][rb+7]));
        unsigned sa0 = __shfl_xor(pa0, 32);
        unsigned sa1 = __shfl_xor(pa1, 32);
        unsigned sb0 = __shfl_xor(pb0, 32);
        unsigned sb1 = __shfl_xor(pb1, 32);
        union { unsigned u[4]; short8 s8; } pa;
        pa.u[0] = hi ? sb0 : pa0;
        pa.u[1] = hi ? sb1 : pa1;
        pa.u[2] = hi ? pb0 : sa0;
        pa.u[3] = hi ? pb1 : sa1;
        const int jc8 = kc * 2 + hi;
        __builtin_amdgcn_s_setprio(1);
#pragma unroll
        for (int dt = 0; dt < 4; ++dt) {
            int d = dt * 32 + l31;
            short8 bf = *reinterpret_cast<const short8*>(
                &CVT[d * 128 + ((jc8 ^ (d & 7)) << 3)]);
            acc[dt] = __builtin_amdgcn_mfma_f32_32x32x16_bf16(pa.s8, bf, acc[dt], 0, 0, 0);
        }
        __builtin_amdgcn_s_setprio(0);
    }

    wfac[wv][l31] = w[(size_t)t * (H_ * 3) + h * 3 + 0] * linv;
    __syncthreads();

    float wfr[16];
#pragma unroll
    for (int r = 0; r < 16; ++r)
        wfr[r] = wfac[wv][(r & 3) + 8 * (r >> 2) + hi4];
#pragma unroll
    for (int dt = 0; dt < 4; ++dt)
#pragma unroll
        for (int r = 0; r < 16; ++r) {
            int crow = (r & 3) + 8 * (r >> 2) + hi4;
            int tt = t0 + (crow & 15);
            int hh = kh * G_ + 2 * wv + (crow >> 4);
            out[(size_t)tt * (H_ * D_) + hh * D_ + dt * 32 + l31] = acc[dt][r] * wfr[r];
        }

#pragma unroll
    for (int half = 0; half < 2; ++half) {
        int b  = (tid & 15) + half * 16;
        int qq = tid >> 4;
        int tt = t0 + qq;
        float sc = 0.f;
        int j0 = 4 * b - 1; if (j0 < 0) j0 = 0;
        int j1 = 4 * b + 3; if (j1 > NCMP - 1) j1 = NCMP - 1;
        for (int j = j0; j <= j1; ++j) sc += wsc_s[qq * 132 + j];
        int tb = tt >> 6;
        bool forced = (b == 0) || (b <= tb && b >= tb - 1);
        if (forced) sc = 1e30f;
        if (b * 64 > tt) sc = -1e30f;
        bsc_s[qq * 32 + b] = sc;
    }
    __syncthreads();

#pragma unroll
    for (int half = 0; half < 2; ++half) {
        int b  = (tid & 15) + half * 16;
        int qq = tid >> 4;
        float sb = bsc_s[qq * 32 + b];
        int cnt = 0;
        for (int b2 = 0; b2 < NBLK; ++b2) {
            float s2 = bsc_s[qq * 32 + b2];
            cnt += (s2 > sb) || (s2 == sb && b2 < b);
        }
        if (cnt < TOPN) atomicOr(&sel_s[qq], 1u << b);
    }
    __syncthreads();
    if (tid < 16) sel[kh * T_ + t0 + tid] = sel_s[tid];
}

// ---------- kernel 3: MFMA flash window+selected attention (REWRITTEN) --------
// 1024 blocks x 2 waves (head-pair split): grid (128, KH, 4), z = phase*2+hpair.
// Single-buffered 32KB LDS -> 4 blocks/CU. exp2 domain (SCALE*log2e folded into
// Q cast). Interior tiles skip the per-element mask; defer-max (THR=8) skips
// max-reduce + acc rescale on the common path. m_run is wave-uniform.
__global__ __launch_bounds__(128, 2) void slc_win_mfma(
        const float* __restrict__ q, const unsigned short* __restrict__ kimg,
        const unsigned short* __restrict__ vtimg, const float* __restrict__ w,
        const unsigned int* __restrict__ sel, float* __restrict__ out,
        float* __restrict__ winb, float* __restrict__ slcb, int use_scratch) {
    const int phase = blockIdx.z >> 1;
    const int hpair = blockIdx.z & 1;
    const int qt    = phase ? ((int)gridDim.x - 1 - (int)blockIdx.x) : (int)blockIdx.x;
    const int kh    = blockIdx.y;
    const int t0    = qt * 16;
    const int tid   = threadIdx.x;
    const int wv    = tid >> 6;        // 0..1
    const int lane  = tid & 63;
    const int l31   = lane & 31;
    const int hi    = lane >> 5;
    const int hi4   = hi * 4;

    __shared__ unsigned short Kl[64 * 128];   // 16 KB
    __shared__ unsigned short Vt[128 * 64];   // 16 KB
    __shared__ float wfac[2][32];

    const int qloc = l31 & 15;
    const int t    = t0 + qloc;
    const int hloc = hpair * 4 + wv * 2 + (l31 >> 4);
    const int h    = kh * G_ + hloc;

    // Q fragment, pre-scaled: logits come out of MFMA already in exp2 domain
    short8 qf[8];
    {
        const float* qrow = q + (size_t)t * (H_ * D_) + h * D_;
#pragma unroll
        for (int dc = 0; dc < 8; ++dc) {
            int d0 = dc * 16 + hi * 8;
            float4 x = *reinterpret_cast<const float4*>(qrow + d0);
            float4 y = *reinterpret_cast<const float4*>(qrow + d0 + 4);
            short8 f;
            f[0] = (short)f2bf(x.x * SCL2); f[1] = (short)f2bf(x.y * SCL2);
            f[2] = (short)f2bf(x.z * SCL2); f[3] = (short)f2bf(x.w * SCL2);
            f[4] = (short)f2bf(y.x * SCL2); f[5] = (short)f2bf(y.y * SCL2);
            f[6] = (short)f2bf(y.z * SCL2); f[7] = (short)f2bf(y.w * SCL2);
            qf[dc] = f;
        }
    }

    const unsigned int smask = sel[kh * T_ + t];
    const int tbmax = t0 >> 6;
    unsigned int rem = 0;
    int bidx = 0;
    if (phase == 0) {
        int lo = t0 - (WIN_ - 1); if (lo < 0) lo = 0;
        bidx = lo >> 6;
    } else {
        unsigned int vm = (tbmax >= 31) ? 0xffffffffu : ((2u << tbmax) - 1u);
        rem = smask;
        rem |= __shfl_xor(rem, 1); rem |= __shfl_xor(rem, 2);
        rem |= __shfl_xor(rem, 4); rem |= __shfl_xor(rem, 8);
        rem &= vm;
    }

    f32x16 acc[4];
#pragma unroll
    for (int dt = 0; dt < 4; ++dt)
#pragma unroll
        for (int r = 0; r < 16; ++r) acc[dt][r] = 0.f;
    float m_run = -1e30f, l_run = 0.f;

    int b_cur;
    if (phase == 0) b_cur = bidx++;
    else { b_cur = rem ? (__ffs(rem) - 1) : -1; if (rem) rem &= rem - 1; }

    while (b_cur >= 0) {
        __syncthreads();   // prev tile fully consumed (WAR on single buffer)
        {
            const size_t tb = ((size_t)kh * 32 + b_cur) * 8192;
#pragma unroll
            for (int it = 0; it < 8; ++it) {
                int off = (wv * 8 + it) * 512;
                GLD16(kimg + tb + off + lane * 8, &Kl[off]);
            }
#pragma unroll
            for (int it = 0; it < 8; ++it) {
                int off = (wv * 8 + it) * 512;
                GLD16(vtimg + tb + off + lane * 8, &Vt[off]);
            }
        }
        __syncthreads();   // data ready (compiler drains vmcnt here)

        const int s0 = b_cur << 6;

        // ---- QK^T (swapped): S^T[key][combo], pre-scaled logits ----
        f32x16 s_[2];
#pragma unroll
        for (int r = 0; r < 16; ++r) { s_[0][r] = 0.f; s_[1][r] = 0.f; }
        __builtin_amdgcn_s_setprio(1);
#pragma unroll
        for (int dc = 0; dc < 8; ++dc) {
            int c8 = dc * 2 + hi;
            int swz = (c8 ^ (l31 & 7)) << 3;
            short8 a0 = *reinterpret_cast<const short8*>(&Kl[l31 * 128 + swz]);
            short8 a1 = *reinterpret_cast<const short8*>(&Kl[(32 + l31) * 128 + swz]);
            s_[0] = __builtin_amdgcn_mfma_f32_32x32x16_bf16(a0, qf[dc], s_[0], 0, 0, 0);
            s_[1] = __builtin_amdgcn_mfma_f32_32x32x16_bf16(a1, qf[dc], s_[1], 0, 0, 0);
        }
        __builtin_amdgcn_s_setprio(0);

        // ---- masking: per-element only on boundary tiles ----
        const int sb = (smask >> b_cur) & 1;
        const bool needmask = (b_cur == tbmax) ||
                              ((phase == 0) && (s0 + 496 < t0));
        float mc = -1e30f;
        if (needmask) {
#pragma unroll
            for (int sub = 0; sub < 2; ++sub)
#pragma unroll
                for (int r = 0; r < 16; ++r) {
                    int crow = (r & 3) + 8 * (r >> 2) + hi4;
                    int s = s0 + sub * 32 + crow;
                    bool ok = (s <= t) && (phase ? (sb != 0) : (s + WIN_ > t));
                    float lg = ok ? s_[sub][r] : -1e30f;
                    s_[sub][r] = lg;
                    mc = fmaxf(mc, lg);
                }
        } else {
#pragma unroll
            for (int sub = 0; sub < 2; ++sub)
#pragma unroll
                for (int r = 0; r < 16; ++r) mc = fmaxf(mc, s_[sub][r]);
            if (phase) mc = sb ? mc : -1e30f;
        }

        // ---- defer-max: rescale only when the wave's max grew past THR2 ----
        float f = 1.f;
        const bool resc = !__all(mc <= m_run + THR2);
        if (resc) {
            float wm = mc;
            wm = fmaxf(wm, __shfl_xor(wm, 1));
            wm = fmaxf(wm, __shfl_xor(wm, 2));
            wm = fmaxf(wm, __shfl_xor(wm, 4));
            wm = fmaxf(wm, __shfl_xor(wm, 8));
            wm = fmaxf(wm, __shfl_xor(wm, 16));
            wm = fmaxf(wm, __shfl_xor(wm, 32));
            float mnew = fmaxf(m_run, wm);
            f = exp2_fast(m_run - mnew);
            m_run = mnew;
        }

        // ---- p = 2^(s - m), row sum ----
        float lsum = 0.f;
#pragma unroll
        for (int sub = 0; sub < 2; ++sub)
#pragma unroll
            for (int r = 0; r < 16; ++r) {
                float e = exp2_fast(s_[sub][r] - m_run);
                s_[sub][r] = e;
                lsum += e;
            }
        if (phase && !sb) lsum = 0.f;       // row fully deselected (fast path)
        lsum += __shfl_xor(lsum, 32);
        if (resc) {
            l_run = l_run * f + lsum;
#pragma unroll
            for (int dt = 0; dt < 4; ++dt)
#pragma unroll
                for (int r = 0; r < 16; ++r) acc[dt][r] *= f;
        } else {
            l_run += lsum;
        }

        // ---- P -> bf16 A-frags (zeroed for deselected rows); PV ----
        const unsigned zm = (phase && !sb) ? 0u : 0xffffffffu;
#pragma unroll
        for (int kc = 0; kc < 4; ++kc) {
            const int su = kc >> 1, rb = (kc & 1) * 8;
            unsigned pa0, pb0, pa1, pb1;
            asm("v_cvt_pk_bf16_f32 %0, %1, %2" : "=v"(pa0) : "v"(s_[su][rb+0]), "v"(s_[su][rb+1]));
            asm("v_cvt_pk_bf16_f32 %0, %1, %2" : "=v"(pa1) : "v"(s_[su][rb+2]), "v"(s_[su][rb+3]));
            asm("v_cvt_pk_bf16_f32 %0, %1, %2" : "=v"(pb0) : "v"(s_[su][rb+4]), "v"(s_[su][rb+5]));
            asm("v_cvt_pk_bf16_f32 %0, %1, %2" : "=v"(pb1) : "v"(s_[su][rb+6]), "v"(s_[su][rb+7]));
            unsigned sa0 = __shfl_xor(pa0, 32);
            unsigned sa1 = __shfl_xor(pa1, 32);
            unsigned sb0 = __shfl_xor(pb0, 32);
            unsigned sb1 = __shfl_xor(pb1, 32);
            union { unsigned u[4]; short8 s8; } pa;
            pa.u[0] = (hi ? sb0 : pa0) & zm;
            pa.u[1] = (hi ? sb1 : pa1) & zm;
            pa.u[2] = (hi ? pb0 : sa0) & zm;
            pa.u[3] = (hi ? pb1 : sa1) & zm;
            const int kc8 = kc * 2 + hi;
            __builtin_amdgcn_s_setprio(1);
#pragma unroll
            for (int dt = 0; dt < 4; ++dt) {
                int d = dt * 32 + l31;
                short8 bf = *reinterpret_cast<const short8*>(
                    &Vt[d * 64 + ((kc8 ^ (d & 7)) << 3)]);
                acc[dt] = __builtin_amdgcn_mfma_f32_32x32x16_bf16(pa.s8, bf, acc[dt], 0, 0, 0);
            }
            __builtin_amdgcn_s_setprio(0);
        }

        if (phase == 0) b_cur = (bidx <= tbmax) ? bidx++ : -1;
        else { b_cur = rem ? (__ffs(rem) - 1) : -1; if (rem) rem &= rem - 1; }
    }

    // ---- epilogue ----
    float linv = 1.f / l_run;
    int widx = (phase == 0) ? 2 : 1;
    wfac[wv][l31] = w[(size_t)t * (H_ * 3) + h * 3 + widx] * linv;
    __syncthreads();
    float wfr[16];
#pragma unroll
    for (int r = 0; r < 16; ++r)
        wfr[r] = wfac[wv][(r & 3) + 8 * (r >> 2) + hi4];
    float* base = (phase == 0) ? winb : slcb;
#pragma unroll
    for (int dt = 0; dt < 4; ++dt)
#pragma unroll
        for (int r = 0; r < 16; ++r) {
            int crow = (r & 3) + 8 * (r >> 2) + hi4;
            int tt = t0 + (crow & 15);
            int hh = kh * G_ + hpair * 4 + wv * 2 + (crow >> 4);
            size_t idx = (size_t)tt * (H_ * D_) + hh * D_ + dt * 32 + l31;
            float val = acc[dt][r] * wfr[r];
            if (use_scratch) base[idx] = val;
            else             atomicAdd(&out[idx], val);
        }
}

// ---------- kernel 4: combine (unchanged) -------------------------------------
__global__ __launch_bounds__(256) void combine_out(float* __restrict__ out,
        const float* __restrict__ a, const float* __restrict__ b) {
    int i = blockIdx.x * 256 + threadIdx.x;
    float4 o = reinterpret_cast<float4*>(out)[i];
    float4 x = reinterpret_cast<const float4*>(a)[i];
    float4 y = reinterpret_cast<const float4*>(b)[i];
    o.x += x.x + y.x; o.y += x.y + y.y; o.z += x.z + y.z; o.w += x.w + y.w;
    reinterpret_cast<float4*>(out)[i] = o;
}

// ---------- launch ----------
extern "C" void kernel_launch(void* const* d_in, const int* in_sizes, int n_in,
                              void* d_out, int out_size, void* d_ws, size_t ws_size,
                              hipStream_t stream) {
    const float* q = (const float*)d_in[0];
    const float* k = (const float*)d_in[1];
    const float* v = (const float*)d_in[2];
    const float* w = (const float*)d_in[3];
    float* out = (float*)d_out;

    char* ws = (char*)d_ws;
    unsigned short* kimg  = (unsigned short*)(ws);                    // 1 MB
    unsigned short* vtimg = (unsigned short*)(ws + (1u << 20));       // 1 MB
    unsigned short* khiI  = (unsigned short*)(ws + (2u << 20));       // 64 KB
    unsigned short* kloI  = (unsigned short*)(ws + (2u << 20) + 65536);
    unsigned short* cvtI  = (unsigned short*)(ws + (2u << 20) + 2 * 65536);
    unsigned short* vflat = (unsigned short*)(ws + (2u << 20) + 3 * 65536);
    unsigned int*   sel   = (unsigned int*)(ws + (2u << 20) + 4 * 65536);  // 16 KB
    float* winb_s = (float*)(ws + (2u << 20) + 4 * 65536 + 16384);
    float* slcb_s = winb_s + (size_t)T_ * H_ * D_;
    const size_t need = (2u << 20) + 4 * 65536 + 16384
                        + 2 * (size_t)T_ * H_ * D_ * sizeof(float);
    const int use_scratch = (ws_size >= need) ? 1 : 0;
    float* winb = use_scratch ? winb_s : out;
    float* slcb = use_scratch ? slcb_s : out;

    hipLaunchKernelGGL(prep_kv, dim3(32, KH_), dim3(256), 0, stream, k, v, kimg, vtimg);
    hipLaunchKernelGGL(build_cmp, dim3(128, KH_), dim3(128), 0, stream,
                       k, v, khiI, kloI, vflat);
    hipLaunchKernelGGL(prep_cmp_img, dim3(KH_), dim3(256), 0, stream, vflat, cvtI);
    hipLaunchKernelGGL(cmp_attn_mfma, dim3(T_ / 16, KH_), dim3(256), 0, stream,
                       q, w, khiI, kloI, cvtI, out, sel);
    hipLaunchKernelGGL(slc_win_mfma, dim3(T_ / 16, KH_, 4), dim3(128), 0, stream,
                       q, kimg, vtimg, w, sel, out, winb, slcb, use_scratch);
    if (use_scratch) {
        hipLaunchKernelGGL(combine_out, dim3((T_ * H_ * D_ / 4) / 256), dim3(256), 0, stream,
                           out, winb, slcb);
    }
}